// Round 1
// baseline (458.954 us; speedup 1.0000x reference)
//
#include <hip/hip_runtime.h>
#include <hip/hip_bf16.h>
#include <math.h>

#define N_NODES 50000
#define N_EDGES 600000
#define N_GRAPHS 1024
#define H 128
#define BN_EPS 1e-5f

// ---------------- degree / CSR build ----------------

__global__ void k_count(const int* __restrict__ src, const int* __restrict__ dst,
                        int* __restrict__ cntO, int* __restrict__ cntI, int E) {
    int i = blockIdx.x * blockDim.x + threadIdx.x;
    if (i < E) {
        atomicAdd(&cntO[src[i]], 1);
        atomicAdd(&cntI[dst[i]], 1);
    }
}

// single-block exclusive scan over n counts -> row_ptr[0..n]
__global__ void k_scan(const int* __restrict__ cnt, int* __restrict__ row_ptr, int n) {
    __shared__ int tot[1024];
    int t = threadIdx.x;
    int chunk = (n + 1023) / 1024;
    int beg = t * chunk;
    int end = min(beg + chunk, n);
    int s = 0;
    for (int i = beg; i < end; ++i) s += cnt[i];
    tot[t] = s;
    __syncthreads();
    for (int off = 1; off < 1024; off <<= 1) {
        int v = (t >= off) ? tot[t - off] : 0;
        __syncthreads();
        tot[t] += v;
        __syncthreads();
    }
    int run = (t == 0) ? 0 : tot[t - 1];
    for (int i = beg; i < end; ++i) { row_ptr[i] = run; run += cnt[i]; }
    if (t == 1023) row_ptr[n] = tot[1023];
}

__global__ void k_fill(const int* __restrict__ src, const int* __restrict__ dst,
                       int* __restrict__ cursor, int* __restrict__ col, int E) {
    int i = blockIdx.x * blockDim.x + threadIdx.x;
    if (i < E) {
        int p = atomicAdd(&cursor[dst[i]], 1);
        col[p] = src[i];
    }
}

__global__ void k_norm(const int* __restrict__ cntO, const int* __restrict__ cntI,
                       float* __restrict__ oi, float* __restrict__ ii, int n) {
    int i = blockIdx.x * blockDim.x + threadIdx.x;
    if (i < n) {
        oi[i] = rsqrtf(fmaxf((float)cntO[i], 1.f));
        ii[i] = rsqrtf(fmaxf((float)cntI[i], 1.f));
    }
}

// ---------------- node pipeline ----------------

__global__ void k_embed(const int* __restrict__ feat, const float* __restrict__ emb,
                        float* __restrict__ out, int n) {
    int i = blockIdx.x * blockDim.x + threadIdx.x;
    if (i < n * 32) {
        int node = i >> 5, c4 = i & 31;
        ((float4*)out)[i] = ((const float4*)(emb + feat[node] * H))[c4];
    }
}

// one wave per dst node; 64 lanes x 2 channels; sum oi[src]*h[src] over in-edges
__global__ void k_gather(const float* __restrict__ h, const float* __restrict__ oi,
                         const int* __restrict__ row_ptr, const int* __restrict__ col,
                         float* __restrict__ out, int n) {
    int gid = blockIdx.x * blockDim.x + threadIdx.x;
    int node = gid >> 6;
    int lane = gid & 63;
    if (node >= n) return;
    int beg = row_ptr[node];
    int end = row_ptr[node + 1];
    float2 acc = make_float2(0.f, 0.f);
    for (int e = beg; e < end; ++e) {
        int s = col[e];
        float sc = oi[s];
        float2 v = *(const float2*)(h + (size_t)s * H + lane * 2);
        acc.x += v.x * sc;
        acc.y += v.y * sc;
    }
    *(float2*)(out + (size_t)node * H + lane * 2) = acc;
}

// out[n][j] = relu( (in[n][:]*ii[n]) @ W + b[j] ), 16-row tile, 256 threads
#define TROWS 16
__global__ void k_transform(const float* __restrict__ in, const float* __restrict__ ii,
                            const float* __restrict__ W, const float* __restrict__ b,
                            float* __restrict__ out, int n) {
    __shared__ float At[TROWS][H];
    int block0 = blockIdx.x * TROWS;
    int tid = threadIdx.x;
    for (int i = tid; i < TROWS * H; i += 256) {
        int r = i >> 7, c = i & 127;
        int node = block0 + r;
        At[r][c] = (node < n) ? in[(size_t)node * H + c] * ii[node] : 0.f;
    }
    __syncthreads();
    int j = tid & 127;
    int ty = tid >> 7;  // 0..1, each handles 8 rows
    float acc[8];
#pragma unroll
    for (int r = 0; r < 8; ++r) acc[r] = 0.f;
    for (int k = 0; k < H; ++k) {
        float w = W[k * H + j];
#pragma unroll
        for (int r = 0; r < 8; ++r) acc[r] += At[ty * 8 + r][k] * w;
    }
    float bj = b[j];
#pragma unroll
    for (int r = 0; r < 8; ++r) {
        int node = block0 + ty * 8 + r;
        if (node < n) out[(size_t)node * H + j] = fmaxf(acc[r] + bj, 0.f);
    }
}

// per-graph mean via binary search over sorted graph_ids; block per graph, 128 threads
__global__ void k_pool(const float* __restrict__ h, const int* __restrict__ gid,
                       float* __restrict__ hg, int n) {
    int g = blockIdx.x;
    __shared__ int sh[2];
    if (threadIdx.x == 0) {
        int lo = 0, hi = n;
        while (lo < hi) { int m = (lo + hi) >> 1; if (gid[m] < g) lo = m + 1; else hi = m; }
        sh[0] = lo;
        int lo2 = lo, hi2 = n;
        while (lo2 < hi2) { int m = (lo2 + hi2) >> 1; if (gid[m] < g + 1) lo2 = m + 1; else hi2 = m; }
        sh[1] = lo2;
    }
    __syncthreads();
    int beg = sh[0], end = sh[1];
    int c = threadIdx.x;
    float s = 0.f;
    for (int i = beg; i < end; ++i) s += h[(size_t)i * H + c];
    float cnt = (float)(end - beg);
    hg[g * H + c] = s / fmaxf(cnt, 1.f);
}

// ---------------- MLP head ----------------

// block per row (1024 rows), 128 threads; out[g][j] = act(in[g][:]@W[:,j] + b[j])
__global__ void k_mlp(const float* __restrict__ in, const float* __restrict__ W,
                      const float* __restrict__ b, float* __restrict__ out,
                      int K, int J, float slope, int act) {
    __shared__ float ld[128];
    int g = blockIdx.x;
    int t = threadIdx.x;
    if (t < K) ld[t] = in[g * K + t];
    __syncthreads();
    if (t < J) {
        float acc = b[t];
        for (int k = 0; k < K; ++k) acc += ld[k] * W[k * J + t];
        if (act) acc = (acc >= 0.f) ? acc : slope * acc;
        out[g * J + t] = acc;
    }
}

// channel stats over G rows: stats[c]=mu, stats[128+c]=biased var
__global__ void k_bnstat(const float* __restrict__ x, float* __restrict__ stats, int G) {
    int c = blockIdx.x;
    float s = 0.f, s2 = 0.f;
    for (int g = threadIdx.x; g < G; g += blockDim.x) {
        float v = x[g * H + c];
        s += v; s2 += v * v;
    }
    __shared__ float rs[256], rs2[256];
    rs[threadIdx.x] = s; rs2[threadIdx.x] = s2;
    __syncthreads();
    for (int off = 128; off > 0; off >>= 1) {
        if (threadIdx.x < off) { rs[threadIdx.x] += rs[threadIdx.x + off]; rs2[threadIdx.x] += rs2[threadIdx.x + off]; }
        __syncthreads();
    }
    if (threadIdx.x == 0) {
        float mu = rs[0] / G;
        stats[c] = mu;
        stats[H + c] = rs2[0] / G - mu * mu;
    }
}

__global__ void k_bnapply(const float* __restrict__ x, const float* __restrict__ stats,
                          const float* __restrict__ gam, const float* __restrict__ bet,
                          float* __restrict__ out, int G) {
    int i = blockIdx.x * blockDim.x + threadIdx.x;
    if (i < G * H) {
        int c = i & 127;
        float v = (x[i] - stats[c]) * rsqrtf(stats[H + c] + BN_EPS) * gam[c] + bet[c];
        out[i] = (v >= 0.f) ? v : 0.05f * v;
    }
}

// y = h4 @ e5_w + e5_b; log_softmax over 2 classes
__global__ void k_final(const float* __restrict__ h4, const float* __restrict__ w,
                        const float* __restrict__ b, float* __restrict__ out, int G) {
    int g = blockIdx.x * blockDim.x + threadIdx.x;
    if (g < G) {
        float y0 = b[0], y1 = b[1];
        for (int k = 0; k < 32; ++k) {
            float v = h4[g * 32 + k];
            y0 += v * w[k * 2];
            y1 += v * w[k * 2 + 1];
        }
        float m = fmaxf(y0, y1);
        float l = m + logf(expf(y0 - m) + expf(y1 - m));
        out[g * 2] = y0 - l;
        out[g * 2 + 1] = y1 - l;
    }
}

extern "C" void kernel_launch(void* const* d_in, const int* in_sizes, int n_in,
                              void* d_out, int out_size, void* d_ws, size_t ws_size,
                              hipStream_t stream) {
    const int*   node_feat = (const int*)d_in[0];
    const int*   edge_src  = (const int*)d_in[1];
    const int*   edge_dst  = (const int*)d_in[2];
    const int*   graph_ids = (const int*)d_in[3];
    const float* emb  = (const float*)d_in[4];
    const float* W1   = (const float*)d_in[5];
    const float* b1   = (const float*)d_in[6];
    const float* W2   = (const float*)d_in[7];
    const float* b2   = (const float*)d_in[8];
    const float* e1_w = (const float*)d_in[9];
    const float* e1_b = (const float*)d_in[10];
    const float* e2_w = (const float*)d_in[11];
    const float* e2_b = (const float*)d_in[12];
    const float* e3_w = (const float*)d_in[13];
    const float* e3_b = (const float*)d_in[14];
    const float* e4_w = (const float*)d_in[15];
    const float* e4_b = (const float*)d_in[16];
    const float* e5_w = (const float*)d_in[17];
    const float* e5_b = (const float*)d_in[18];
    const float* bn0_g = (const float*)d_in[19];
    const float* bn0_b = (const float*)d_in[20];
    const float* bn1_g = (const float*)d_in[21];
    const float* bn1_b = (const float*)d_in[22];
    float* out = (float*)d_out;

    // workspace layout (floats)
    float* ws = (float*)d_ws;
    float* bufA = ws;                       // 6,400,000
    float* bufB = bufA + (size_t)N_NODES * H;
    int*   cntO = (int*)(bufB + (size_t)N_NODES * H);  // 50000
    int*   cntI = cntO + N_NODES;                      // 50000 (contiguous with cntO)
    float* oi   = (float*)(cntI + N_NODES);
    float* ii   = oi + N_NODES;
    int*   row_ptr = (int*)(ii + N_NODES);   // 50001 -> pad 50048
    int*   cursor  = row_ptr + 50048;        // 50000 -> pad 50048
    int*   col  = cursor + 50048;            // 600000
    float* hg   = (float*)(col + N_EDGES);   // 131072
    float* t1   = hg + N_GRAPHS * H;         // 131072
    float* t2   = t1 + N_GRAPHS * H;         // 131072
    float* t3   = t2 + N_GRAPHS * H;         // 65536
    float* t4   = t3 + N_GRAPHS * 64;        // 32768
    float* stats = t4 + N_GRAPHS * 32;       // 256

    // zero degree counters
    hipMemsetAsync(cntO, 0, 2 * N_NODES * sizeof(int), stream);

    const int eb = (N_EDGES + 255) / 256;
    k_count<<<eb, 256, 0, stream>>>(edge_src, edge_dst, cntO, cntI, N_EDGES);
    k_scan<<<1, 1024, 0, stream>>>(cntI, row_ptr, N_NODES);
    hipMemcpyAsync(cursor, row_ptr, N_NODES * sizeof(int), hipMemcpyDeviceToDevice, stream);
    k_fill<<<eb, 256, 0, stream>>>(edge_src, edge_dst, cursor, col, N_EDGES);
    k_norm<<<(N_NODES + 255) / 256, 256, 0, stream>>>(cntO, cntI, oi, ii, N_NODES);

    k_embed<<<(N_NODES * 32 + 255) / 256, 256, 0, stream>>>(node_feat, emb, bufA, N_NODES);

    const int gb = (N_NODES * 64 + 255) / 256;
    const int tb = (N_NODES + TROWS - 1) / TROWS;

    // layer 1
    k_gather<<<gb, 256, 0, stream>>>(bufA, oi, row_ptr, col, bufB, N_NODES);
    k_transform<<<tb, 256, 0, stream>>>(bufB, ii, W1, b1, bufA, N_NODES);
    // layer 2
    k_gather<<<gb, 256, 0, stream>>>(bufA, oi, row_ptr, col, bufB, N_NODES);
    k_transform<<<tb, 256, 0, stream>>>(bufB, ii, W2, b2, bufA, N_NODES);

    // pooling
    k_pool<<<N_GRAPHS, 128, 0, stream>>>(bufA, graph_ids, hg, N_NODES);

    // MLP head
    k_mlp<<<N_GRAPHS, 128, 0, stream>>>(hg, e1_w, e1_b, t1, 128, 128, 0.f, 0);
    k_bnstat<<<H, 256, 0, stream>>>(t1, stats, N_GRAPHS);
    k_bnapply<<<(N_GRAPHS * H + 255) / 256, 256, 0, stream>>>(t1, stats, bn0_g, bn0_b, t2, N_GRAPHS);

    k_mlp<<<N_GRAPHS, 128, 0, stream>>>(t2, e2_w, e2_b, t1, 128, 128, 0.f, 0);
    k_bnstat<<<H, 256, 0, stream>>>(t1, stats, N_GRAPHS);
    k_bnapply<<<(N_GRAPHS * H + 255) / 256, 256, 0, stream>>>(t1, stats, bn1_g, bn1_b, t2, N_GRAPHS);

    k_mlp<<<N_GRAPHS, 128, 0, stream>>>(t2, e3_w, e3_b, t3, 128, 64, 0.1f, 1);
    k_mlp<<<N_GRAPHS, 128, 0, stream>>>(t3, e4_w, e4_b, t4, 64, 32, 0.1f, 1);
    k_final<<<(N_GRAPHS + 255) / 256, 256, 0, stream>>>(t4, e5_w, e5_b, out, N_GRAPHS);
}

// Round 2
// 388.993 us; speedup vs baseline: 1.1799x; 1.1799x over previous
//
#include <hip/hip_runtime.h>
#include <hip/hip_bf16.h>
#include <math.h>

#define N_NODES 50000
#define N_EDGES 600000
#define N_GRAPHS 1024
#define H 128
#define BN_EPS 1e-5f
#define SCAN_BLOCKS ((N_NODES + 255) / 256)   // 196

// ---------------- degree / CSR build ----------------

__global__ void k_count(const int* __restrict__ src, const int* __restrict__ dst,
                        int* __restrict__ cntO, int* __restrict__ cntI, int E) {
    int i = blockIdx.x * blockDim.x + threadIdx.x;
    if (i < E) {
        atomicAdd(&cntO[src[i]], 1);
        atomicAdd(&cntI[dst[i]], 1);
    }
}

// hierarchical scan, stage 1: per-block sums of cnt
__global__ void k_blocksum(const int* __restrict__ cnt, int* __restrict__ bsum, int n) {
    __shared__ int red[256];
    int i = blockIdx.x * 256 + threadIdx.x;
    red[threadIdx.x] = (i < n) ? cnt[i] : 0;
    __syncthreads();
    for (int off = 128; off > 0; off >>= 1) {
        if (threadIdx.x < off) red[threadIdx.x] += red[threadIdx.x + off];
        __syncthreads();
    }
    if (threadIdx.x == 0) bsum[blockIdx.x] = red[0];
}

// stage 2: single small block scans the block sums in place (-> exclusive),
// writes total to row_ptr[n]
__global__ void k_scanbsum(int* __restrict__ bsum, int* __restrict__ row_ptr_last, int nb) {
    __shared__ int sh[256];
    int t = threadIdx.x;
    int v = (t < nb) ? bsum[t] : 0;
    sh[t] = v;
    __syncthreads();
    for (int off = 1; off < 256; off <<= 1) {
        int u = (t >= off) ? sh[t - off] : 0;
        __syncthreads();
        sh[t] += u;
        __syncthreads();
    }
    if (t < nb) bsum[t] = sh[t] - v;            // exclusive
    if (t == nb - 1) *row_ptr_last = sh[t];      // grand total
}

// stage 3: per-block exclusive scan + block offset -> row_ptr and cursor
__global__ void k_scatterscan(const int* __restrict__ cnt, const int* __restrict__ bsum,
                              int* __restrict__ row_ptr, int* __restrict__ cursor, int n) {
    __shared__ int sh[256];
    int i = blockIdx.x * 256 + threadIdx.x;
    int t = threadIdx.x;
    int v = (i < n) ? cnt[i] : 0;
    sh[t] = v;
    __syncthreads();
    for (int off = 1; off < 256; off <<= 1) {
        int u = (t >= off) ? sh[t - off] : 0;
        __syncthreads();
        sh[t] += u;
        __syncthreads();
    }
    if (i < n) {
        int ex = bsum[blockIdx.x] + sh[t] - v;
        row_ptr[i] = ex;
        cursor[i] = ex;
    }
}

__global__ void k_fill(const int* __restrict__ src, const int* __restrict__ dst,
                       int* __restrict__ cursor, int* __restrict__ col, int E) {
    int i = blockIdx.x * blockDim.x + threadIdx.x;
    if (i < E) {
        int p = atomicAdd(&cursor[dst[i]], 1);
        col[p] = src[i];
    }
}

__global__ void k_norm(const int* __restrict__ cntO, const int* __restrict__ cntI,
                       float* __restrict__ oi, float* __restrict__ ii, int n) {
    int i = blockIdx.x * blockDim.x + threadIdx.x;
    if (i < n) {
        oi[i] = rsqrtf(fmaxf((float)cntO[i], 1.f));
        ii[i] = rsqrtf(fmaxf((float)cntI[i], 1.f));
    }
}

// ---------------- node pipeline ----------------

__global__ void k_embed(const int* __restrict__ feat, const float* __restrict__ emb,
                        float* __restrict__ out, int n) {
    int i = blockIdx.x * blockDim.x + threadIdx.x;
    if (i < n * 32) {
        int node = i >> 5, c4 = i & 31;
        ((float4*)out)[i] = ((const float4*)(emb + feat[node] * H))[c4];
    }
}

// one wave per dst node; 64 lanes x 2 channels; sum oi[src]*h[src] over in-edges
__global__ void k_gather(const float* __restrict__ h, const float* __restrict__ oi,
                         const int* __restrict__ row_ptr, const int* __restrict__ col,
                         float* __restrict__ out, int n) {
    int gid = blockIdx.x * blockDim.x + threadIdx.x;
    int node = gid >> 6;
    int lane = gid & 63;
    if (node >= n) return;
    int beg = row_ptr[node];
    int end = row_ptr[node + 1];
    float2 acc = make_float2(0.f, 0.f);
    for (int e = beg; e < end; ++e) {
        int s = col[e];
        float sc = oi[s];
        float2 v = *(const float2*)(h + (size_t)s * H + lane * 2);
        acc.x += v.x * sc;
        acc.y += v.y * sc;
    }
    *(float2*)(out + (size_t)node * H + lane * 2) = acc;
}

// out[n][j] = relu( (in[n][:]*ii[n]) @ W + b[j] ), 16-row tile, 256 threads
#define TROWS 16
__global__ void k_transform(const float* __restrict__ in, const float* __restrict__ ii,
                            const float* __restrict__ W, const float* __restrict__ b,
                            float* __restrict__ out, int n) {
    __shared__ float At[TROWS][H];
    int block0 = blockIdx.x * TROWS;
    int tid = threadIdx.x;
    for (int i = tid; i < TROWS * H; i += 256) {
        int r = i >> 7, c = i & 127;
        int node = block0 + r;
        At[r][c] = (node < n) ? in[(size_t)node * H + c] * ii[node] : 0.f;
    }
    __syncthreads();
    int j = tid & 127;
    int ty = tid >> 7;  // 0..1, each handles 8 rows
    float acc[8];
#pragma unroll
    for (int r = 0; r < 8; ++r) acc[r] = 0.f;
    for (int k = 0; k < H; ++k) {
        float w = W[k * H + j];
#pragma unroll
        for (int r = 0; r < 8; ++r) acc[r] += At[ty * 8 + r][k] * w;
    }
    float bj = b[j];
#pragma unroll
    for (int r = 0; r < 8; ++r) {
        int node = block0 + ty * 8 + r;
        if (node < n) out[(size_t)node * H + j] = fmaxf(acc[r] + bj, 0.f);
    }
}

// per-graph mean via binary search over sorted graph_ids; block per graph, 128 threads
__global__ void k_pool(const float* __restrict__ h, const int* __restrict__ gid,
                       float* __restrict__ hg, int n) {
    int g = blockIdx.x;
    __shared__ int sh[2];
    if (threadIdx.x == 0) {
        int lo = 0, hi = n;
        while (lo < hi) { int m = (lo + hi) >> 1; if (gid[m] < g) lo = m + 1; else hi = m; }
        sh[0] = lo;
        int lo2 = lo, hi2 = n;
        while (lo2 < hi2) { int m = (lo2 + hi2) >> 1; if (gid[m] < g + 1) lo2 = m + 1; else hi2 = m; }
        sh[1] = lo2;
    }
    __syncthreads();
    int beg = sh[0], end = sh[1];
    int c = threadIdx.x;
    float s = 0.f;
    for (int i = beg; i < end; ++i) s += h[(size_t)i * H + c];
    float cnt = (float)(end - beg);
    hg[g * H + c] = s / fmaxf(cnt, 1.f);
}

// ---------------- MLP head ----------------

// block per row (1024 rows), 128 threads; out[g][j] = act(in[g][:]@W[:,j] + b[j])
__global__ void k_mlp(const float* __restrict__ in, const float* __restrict__ W,
                      const float* __restrict__ b, float* __restrict__ out,
                      int K, int J, float slope, int act) {
    __shared__ float ld[128];
    int g = blockIdx.x;
    int t = threadIdx.x;
    if (t < K) ld[t] = in[g * K + t];
    __syncthreads();
    if (t < J) {
        float acc = b[t];
        for (int k = 0; k < K; ++k) acc += ld[k] * W[k * J + t];
        if (act) acc = (acc >= 0.f) ? acc : slope * acc;
        out[g * J + t] = acc;
    }
}

// channel stats over G rows: stats[c]=mu, stats[128+c]=biased var
__global__ void k_bnstat(const float* __restrict__ x, float* __restrict__ stats, int G) {
    int c = blockIdx.x;
    float s = 0.f, s2 = 0.f;
    for (int g = threadIdx.x; g < G; g += blockDim.x) {
        float v = x[g * H + c];
        s += v; s2 += v * v;
    }
    __shared__ float rs[256], rs2[256];
    rs[threadIdx.x] = s; rs2[threadIdx.x] = s2;
    __syncthreads();
    for (int off = 128; off > 0; off >>= 1) {
        if (threadIdx.x < off) { rs[threadIdx.x] += rs[threadIdx.x + off]; rs2[threadIdx.x] += rs2[threadIdx.x + off]; }
        __syncthreads();
    }
    if (threadIdx.x == 0) {
        float mu = rs[0] / G;
        stats[c] = mu;
        stats[H + c] = rs2[0] / G - mu * mu;
    }
}

__global__ void k_bnapply(const float* __restrict__ x, const float* __restrict__ stats,
                          const float* __restrict__ gam, const float* __restrict__ bet,
                          float* __restrict__ out, int G) {
    int i = blockIdx.x * blockDim.x + threadIdx.x;
    if (i < G * H) {
        int c = i & 127;
        float v = (x[i] - stats[c]) * rsqrtf(stats[H + c] + BN_EPS) * gam[c] + bet[c];
        out[i] = (v >= 0.f) ? v : 0.05f * v;
    }
}

// y = h4 @ e5_w + e5_b; log_softmax over 2 classes
__global__ void k_final(const float* __restrict__ h4, const float* __restrict__ w,
                        const float* __restrict__ b, float* __restrict__ out, int G) {
    int g = blockIdx.x * blockDim.x + threadIdx.x;
    if (g < G) {
        float y0 = b[0], y1 = b[1];
        for (int k = 0; k < 32; ++k) {
            float v = h4[g * 32 + k];
            y0 += v * w[k * 2];
            y1 += v * w[k * 2 + 1];
        }
        float m = fmaxf(y0, y1);
        float l = m + logf(expf(y0 - m) + expf(y1 - m));
        out[g * 2] = y0 - l;
        out[g * 2 + 1] = y1 - l;
    }
}

extern "C" void kernel_launch(void* const* d_in, const int* in_sizes, int n_in,
                              void* d_out, int out_size, void* d_ws, size_t ws_size,
                              hipStream_t stream) {
    const int*   node_feat = (const int*)d_in[0];
    const int*   edge_src  = (const int*)d_in[1];
    const int*   edge_dst  = (const int*)d_in[2];
    const int*   graph_ids = (const int*)d_in[3];
    const float* emb  = (const float*)d_in[4];
    const float* W1   = (const float*)d_in[5];
    const float* b1   = (const float*)d_in[6];
    const float* W2   = (const float*)d_in[7];
    const float* b2   = (const float*)d_in[8];
    const float* e1_w = (const float*)d_in[9];
    const float* e1_b = (const float*)d_in[10];
    const float* e2_w = (const float*)d_in[11];
    const float* e2_b = (const float*)d_in[12];
    const float* e3_w = (const float*)d_in[13];
    const float* e3_b = (const float*)d_in[14];
    const float* e4_w = (const float*)d_in[15];
    const float* e4_b = (const float*)d_in[16];
    const float* e5_w = (const float*)d_in[17];
    const float* e5_b = (const float*)d_in[18];
    const float* bn0_g = (const float*)d_in[19];
    const float* bn0_b = (const float*)d_in[20];
    const float* bn1_g = (const float*)d_in[21];
    const float* bn1_b = (const float*)d_in[22];
    float* out = (float*)d_out;

    // workspace layout (floats)
    float* ws = (float*)d_ws;
    float* bufA = ws;                       // 6,400,000
    float* bufB = bufA + (size_t)N_NODES * H;
    int*   cntO = (int*)(bufB + (size_t)N_NODES * H);  // 50000
    int*   cntI = cntO + N_NODES;                      // 50000 (contiguous with cntO)
    float* oi   = (float*)(cntI + N_NODES);
    float* ii   = oi + N_NODES;
    int*   row_ptr = (int*)(ii + N_NODES);   // 50001 -> pad 50048
    int*   cursor  = row_ptr + 50048;        // 50000 -> pad 50048
    int*   col  = cursor + 50048;            // 600000
    float* hg   = (float*)(col + N_EDGES);   // 131072
    float* t1   = hg + N_GRAPHS * H;         // 131072
    float* t2   = t1 + N_GRAPHS * H;         // 131072
    float* t3   = t2 + N_GRAPHS * H;         // 65536
    float* t4   = t3 + N_GRAPHS * 64;        // 32768
    float* stats = t4 + N_GRAPHS * 32;       // 256
    int*   bsum  = (int*)(stats + 2 * H);    // 256

    // zero degree counters
    hipMemsetAsync(cntO, 0, 2 * N_NODES * sizeof(int), stream);

    const int eb = (N_EDGES + 255) / 256;
    k_count<<<eb, 256, 0, stream>>>(edge_src, edge_dst, cntO, cntI, N_EDGES);
    k_blocksum<<<SCAN_BLOCKS, 256, 0, stream>>>(cntI, bsum, N_NODES);
    k_scanbsum<<<1, 256, 0, stream>>>(bsum, row_ptr + N_NODES, SCAN_BLOCKS);
    k_scatterscan<<<SCAN_BLOCKS, 256, 0, stream>>>(cntI, bsum, row_ptr, cursor, N_NODES);
    k_fill<<<eb, 256, 0, stream>>>(edge_src, edge_dst, cursor, col, N_EDGES);
    k_norm<<<(N_NODES + 255) / 256, 256, 0, stream>>>(cntO, cntI, oi, ii, N_NODES);

    k_embed<<<(N_NODES * 32 + 255) / 256, 256, 0, stream>>>(node_feat, emb, bufA, N_NODES);

    const int gb = (N_NODES * 64 + 255) / 256;
    const int tb = (N_NODES + TROWS - 1) / TROWS;

    // layer 1
    k_gather<<<gb, 256, 0, stream>>>(bufA, oi, row_ptr, col, bufB, N_NODES);
    k_transform<<<tb, 256, 0, stream>>>(bufB, ii, W1, b1, bufA, N_NODES);
    // layer 2
    k_gather<<<gb, 256, 0, stream>>>(bufA, oi, row_ptr, col, bufB, N_NODES);
    k_transform<<<tb, 256, 0, stream>>>(bufB, ii, W2, b2, bufA, N_NODES);

    // pooling
    k_pool<<<N_GRAPHS, 128, 0, stream>>>(bufA, graph_ids, hg, N_NODES);

    // MLP head
    k_mlp<<<N_GRAPHS, 128, 0, stream>>>(hg, e1_w, e1_b, t1, 128, 128, 0.f, 0);
    k_bnstat<<<H, 256, 0, stream>>>(t1, stats, N_GRAPHS);
    k_bnapply<<<(N_GRAPHS * H + 255) / 256, 256, 0, stream>>>(t1, stats, bn0_g, bn0_b, t2, N_GRAPHS);

    k_mlp<<<N_GRAPHS, 128, 0, stream>>>(t2, e2_w, e2_b, t1, 128, 128, 0.f, 0);
    k_bnstat<<<H, 256, 0, stream>>>(t1, stats, N_GRAPHS);
    k_bnapply<<<(N_GRAPHS * H + 255) / 256, 256, 0, stream>>>(t1, stats, bn1_g, bn1_b, t2, N_GRAPHS);

    k_mlp<<<N_GRAPHS, 128, 0, stream>>>(t2, e3_w, e3_b, t3, 128, 64, 0.1f, 1);
    k_mlp<<<N_GRAPHS, 128, 0, stream>>>(t3, e4_w, e4_b, t4, 64, 32, 0.1f, 1);
    k_final<<<(N_GRAPHS + 255) / 256, 256, 0, stream>>>(t4, e5_w, e5_b, out, N_GRAPHS);
}

// Round 3
// 339.162 us; speedup vs baseline: 1.3532x; 1.1469x over previous
//
#include <hip/hip_runtime.h>
#include <hip/hip_bf16.h>
#include <math.h>

#define N_NODES 50000
#define N_EDGES 600000
#define N_GRAPHS 1024
#define H 128
#define BN_EPS 1e-5f
#define SCAN_BLOCKS ((N_NODES + 255) / 256)   // 196

// ---------------- degree / CSR build ----------------

__global__ void k_count(const int* __restrict__ src, const int* __restrict__ dst,
                        int* __restrict__ cntO, int* __restrict__ cntI, int E) {
    int i = blockIdx.x * blockDim.x + threadIdx.x;
    if (i < E) {
        atomicAdd(&cntO[src[i]], 1);
        atomicAdd(&cntI[dst[i]], 1);
    }
}

__global__ void k_blocksum(const int* __restrict__ cnt, int* __restrict__ bsum, int n) {
    __shared__ int red[256];
    int i = blockIdx.x * 256 + threadIdx.x;
    red[threadIdx.x] = (i < n) ? cnt[i] : 0;
    __syncthreads();
    for (int off = 128; off > 0; off >>= 1) {
        if (threadIdx.x < off) red[threadIdx.x] += red[threadIdx.x + off];
        __syncthreads();
    }
    if (threadIdx.x == 0) bsum[blockIdx.x] = red[0];
}

__global__ void k_scanbsum(int* __restrict__ bsum, int* __restrict__ row_ptr_last, int nb) {
    __shared__ int sh[256];
    int t = threadIdx.x;
    int v = (t < nb) ? bsum[t] : 0;
    sh[t] = v;
    __syncthreads();
    for (int off = 1; off < 256; off <<= 1) {
        int u = (t >= off) ? sh[t - off] : 0;
        __syncthreads();
        sh[t] += u;
        __syncthreads();
    }
    if (t < nb) bsum[t] = sh[t] - v;            // exclusive
    if (t == nb - 1) *row_ptr_last = sh[t];      // grand total
}

// per-block exclusive scan + block offset -> row_ptr, cursor; also rsqrt norms
__global__ void k_scatterscan(const int* __restrict__ cntI, const int* __restrict__ cntO,
                              const int* __restrict__ bsum,
                              int* __restrict__ row_ptr, int* __restrict__ cursor,
                              float* __restrict__ oi, float* __restrict__ ii, int n) {
    __shared__ int sh[256];
    int i = blockIdx.x * 256 + threadIdx.x;
    int t = threadIdx.x;
    int v = (i < n) ? cntI[i] : 0;
    sh[t] = v;
    __syncthreads();
    for (int off = 1; off < 256; off <<= 1) {
        int u = (t >= off) ? sh[t - off] : 0;
        __syncthreads();
        sh[t] += u;
        __syncthreads();
    }
    if (i < n) {
        int ex = bsum[blockIdx.x] + sh[t] - v;
        row_ptr[i] = ex;
        cursor[i] = ex;
        ii[i] = rsqrtf(fmaxf((float)v, 1.f));
        oi[i] = rsqrtf(fmaxf((float)cntO[i], 1.f));
    }
}

__global__ void k_fill(const int* __restrict__ src, const int* __restrict__ dst,
                       int* __restrict__ cursor, int* __restrict__ col, int E) {
    int i = blockIdx.x * blockDim.x + threadIdx.x;
    if (i < E) {
        int p = atomicAdd(&cursor[dst[i]], 1);
        col[p] = src[i];
    }
}

// ---------------- node pipeline ----------------

// layer-1 gather straight from the 16KB embedding table (cache-resident):
// agg[dst] = sum over in-edges of oi[src] * emb[feat[src]]
__global__ void k_gather_emb(const int* __restrict__ feat, const float* __restrict__ emb,
                             const float* __restrict__ oi,
                             const int* __restrict__ row_ptr, const int* __restrict__ col,
                             float* __restrict__ out, int n) {
    int gid = blockIdx.x * blockDim.x + threadIdx.x;
    int node = gid >> 6;
    int lane = gid & 63;
    if (node >= n) return;
    int beg = row_ptr[node];
    int end = row_ptr[node + 1];
    float2 acc = make_float2(0.f, 0.f);
    for (int e = beg; e < end; ++e) {
        int s = col[e];
        float sc = oi[s];
        float2 v = *(const float2*)(emb + (size_t)feat[s] * H + lane * 2);
        acc.x += v.x * sc;
        acc.y += v.y * sc;
    }
    *(float2*)(out + (size_t)node * H + lane * 2) = acc;
}

// layer-2 gather over bf16 features (halved traffic + working set)
__global__ void k_gather_bf(const __hip_bfloat16* __restrict__ h, const float* __restrict__ oi,
                            const int* __restrict__ row_ptr, const int* __restrict__ col,
                            float* __restrict__ out, int n) {
    int gid = blockIdx.x * blockDim.x + threadIdx.x;
    int node = gid >> 6;
    int lane = gid & 63;
    if (node >= n) return;
    int beg = row_ptr[node];
    int end = row_ptr[node + 1];
    float2 acc = make_float2(0.f, 0.f);
    for (int e = beg; e < end; ++e) {
        int s = col[e];
        float sc = oi[s];
        float2 v = __bfloat1622float2(*(const __hip_bfloat162*)(h + (size_t)s * H + lane * 2));
        acc.x += v.x * sc;
        acc.y += v.y * sc;
    }
    *(float2*)(out + (size_t)node * H + lane * 2) = acc;
}

// out[n][j] = relu( (in[n][:]*ii[n]) @ W + b[j] ); 16-row tile, 256 threads.
// BF16OUT=1 writes bf16, else f32. Safe in-place (tile staged in LDS first).
#define TROWS 16
template <int BF16OUT>
__global__ void k_transform(const float* in, const float* __restrict__ ii,
                            const float* __restrict__ W, const float* __restrict__ b,
                            void* outp, int n) {
    __shared__ float At[TROWS][H];
    int block0 = blockIdx.x * TROWS;
    int tid = threadIdx.x;
    for (int i = tid; i < TROWS * H; i += 256) {
        int r = i >> 7, c = i & 127;
        int node = block0 + r;
        At[r][c] = (node < n) ? in[(size_t)node * H + c] * ii[node] : 0.f;
    }
    __syncthreads();
    int j = tid & 127;
    int ty = tid >> 7;  // 0..1, each handles 8 rows
    float acc[8];
#pragma unroll
    for (int r = 0; r < 8; ++r) acc[r] = 0.f;
    for (int k = 0; k < H; ++k) {
        float w = W[k * H + j];
#pragma unroll
        for (int r = 0; r < 8; ++r) acc[r] += At[ty * 8 + r][k] * w;
    }
    float bj = b[j];
#pragma unroll
    for (int r = 0; r < 8; ++r) {
        int node = block0 + ty * 8 + r;
        if (node < n) {
            float v = fmaxf(acc[r] + bj, 0.f);
            if (BF16OUT)
                ((__hip_bfloat16*)outp)[(size_t)node * H + j] = __float2bfloat16(v);
            else
                ((float*)outp)[(size_t)node * H + j] = v;
        }
    }
}

// per-graph mean via binary search over sorted graph_ids; block per graph, 128 threads
__global__ void k_pool(const float* __restrict__ h, const int* __restrict__ gid,
                       float* __restrict__ hg, int n) {
    int g = blockIdx.x;
    __shared__ int sh[2];
    if (threadIdx.x == 0) {
        int lo = 0, hi = n;
        while (lo < hi) { int m = (lo + hi) >> 1; if (gid[m] < g) lo = m + 1; else hi = m; }
        sh[0] = lo;
        int lo2 = lo, hi2 = n;
        while (lo2 < hi2) { int m = (lo2 + hi2) >> 1; if (gid[m] < g + 1) lo2 = m + 1; else hi2 = m; }
        sh[1] = lo2;
    }
    __syncthreads();
    int beg = sh[0], end = sh[1];
    int c = threadIdx.x;
    float s = 0.f;
    for (int i = beg; i < end; ++i) s += h[(size_t)i * H + c];
    float cnt = (float)(end - beg);
    hg[g * H + c] = s / fmaxf(cnt, 1.f);
}

// ---------------- MLP head ----------------

// t1 = hg @ e1_w + e1_b   (block per row, 128 threads)
__global__ void k_mlp1(const float* __restrict__ in, const float* __restrict__ W,
                       const float* __restrict__ b, float* __restrict__ out) {
    __shared__ float ld[128];
    int g = blockIdx.x;
    int t = threadIdx.x;
    ld[t] = in[g * H + t];
    __syncthreads();
    float acc = b[t];
    for (int k = 0; k < H; ++k) acc += ld[k] * W[k * H + t];
    out[g * H + t] = acc;
}

// channel stats over G rows: stats[c]=mu, stats[128+c]=biased var
__global__ void k_bnstat(const float* __restrict__ x, float* __restrict__ stats, int G) {
    int c = blockIdx.x;
    float s = 0.f, s2 = 0.f;
    for (int g = threadIdx.x; g < G; g += blockDim.x) {
        float v = x[g * H + c];
        s += v; s2 += v * v;
    }
    __shared__ float rs[256], rs2[256];
    rs[threadIdx.x] = s; rs2[threadIdx.x] = s2;
    __syncthreads();
    for (int off = 128; off > 0; off >>= 1) {
        if (threadIdx.x < off) { rs[threadIdx.x] += rs[threadIdx.x + off]; rs2[threadIdx.x] += rs2[threadIdx.x + off]; }
        __syncthreads();
    }
    if (threadIdx.x == 0) {
        float mu = rs[0] / G;
        stats[c] = mu;
        stats[H + c] = rs2[0] / G - mu * mu;
    }
}

// x = lrelu(bn0(t1)); t2 = x @ e2_w + e2_b
__global__ void k_mlp2bn(const float* __restrict__ t1, const float* __restrict__ stats,
                         const float* __restrict__ gam, const float* __restrict__ bet,
                         const float* __restrict__ W, const float* __restrict__ bias,
                         float* __restrict__ t2) {
    __shared__ float x[128];
    int g = blockIdx.x, t = threadIdx.x;
    float v = t1[g * H + t];
    v = (v - stats[t]) * rsqrtf(stats[H + t] + BN_EPS) * gam[t] + bet[t];
    x[t] = (v >= 0.f) ? v : 0.05f * v;
    __syncthreads();
    float acc = bias[t];
    for (int k = 0; k < H; ++k) acc += x[k] * W[k * H + t];
    t2[g * H + t] = acc;
}

// bn1+lrelu -> e3+lrelu -> e4+lrelu -> e5 -> log_softmax, one block per graph
__global__ void k_head(const float* __restrict__ t2, const float* __restrict__ stats,
                       const float* __restrict__ gam, const float* __restrict__ bet,
                       const float* __restrict__ e3w, const float* __restrict__ e3b,
                       const float* __restrict__ e4w, const float* __restrict__ e4b,
                       const float* __restrict__ e5w, const float* __restrict__ e5b,
                       float* __restrict__ out) {
    __shared__ float x[128], h3[64], h4[32];
    int g = blockIdx.x, t = threadIdx.x;
    float v = t2[g * H + t];
    v = (v - stats[t]) * rsqrtf(stats[H + t] + BN_EPS) * gam[t] + bet[t];
    x[t] = (v >= 0.f) ? v : 0.05f * v;
    __syncthreads();
    if (t < 64) {
        float a = e3b[t];
        for (int k = 0; k < 128; ++k) a += x[k] * e3w[k * 64 + t];
        h3[t] = (a >= 0.f) ? a : 0.1f * a;
    }
    __syncthreads();
    if (t < 32) {
        float a = e4b[t];
        for (int k = 0; k < 64; ++k) a += h3[k] * e4w[k * 32 + t];
        h4[t] = (a >= 0.f) ? a : 0.1f * a;
    }
    __syncthreads();
    if (t == 0) {
        float y0 = e5b[0], y1 = e5b[1];
        for (int k = 0; k < 32; ++k) {
            y0 += h4[k] * e5w[2 * k];
            y1 += h4[k] * e5w[2 * k + 1];
        }
        float m = fmaxf(y0, y1);
        float l = m + logf(expf(y0 - m) + expf(y1 - m));
        out[2 * g] = y0 - l;
        out[2 * g + 1] = y1 - l;
    }
}

extern "C" void kernel_launch(void* const* d_in, const int* in_sizes, int n_in,
                              void* d_out, int out_size, void* d_ws, size_t ws_size,
                              hipStream_t stream) {
    const int*   node_feat = (const int*)d_in[0];
    const int*   edge_src  = (const int*)d_in[1];
    const int*   edge_dst  = (const int*)d_in[2];
    const int*   graph_ids = (const int*)d_in[3];
    const float* emb  = (const float*)d_in[4];
    const float* W1   = (const float*)d_in[5];
    const float* b1   = (const float*)d_in[6];
    const float* W2   = (const float*)d_in[7];
    const float* b2   = (const float*)d_in[8];
    const float* e1_w = (const float*)d_in[9];
    const float* e1_b = (const float*)d_in[10];
    const float* e2_w = (const float*)d_in[11];
    const float* e2_b = (const float*)d_in[12];
    const float* e3_w = (const float*)d_in[13];
    const float* e3_b = (const float*)d_in[14];
    const float* e4_w = (const float*)d_in[15];
    const float* e4_b = (const float*)d_in[16];
    const float* e5_w = (const float*)d_in[17];
    const float* e5_b = (const float*)d_in[18];
    const float* bn0_g = (const float*)d_in[19];
    const float* bn0_b = (const float*)d_in[20];
    const float* bn1_g = (const float*)d_in[21];
    const float* bn1_b = (const float*)d_in[22];
    float* out = (float*)d_out;

    // workspace layout (floats)
    float* ws = (float*)d_ws;
    float* bufA = ws;                                   // N*H f32 (agg / h2, in-place)
    __hip_bfloat16* h1bf = (__hip_bfloat16*)(bufA + (size_t)N_NODES * H);  // N*H bf16
    float* after = (float*)(h1bf + (size_t)N_NODES * H);
    int*   cntO = (int*)after;                          // 50000
    int*   cntI = cntO + N_NODES;                       // 50000
    float* oi   = (float*)(cntI + N_NODES);
    float* ii   = oi + N_NODES;
    int*   row_ptr = (int*)(ii + N_NODES);              // 50001 -> pad 50048
    int*   cursor  = row_ptr + 50048;                   // 50000 -> pad 50048
    int*   col  = cursor + 50048;                       // 600000
    float* hg   = (float*)(col + N_EDGES);              // 131072
    float* t1   = hg + N_GRAPHS * H;                    // 131072
    float* t2   = t1 + N_GRAPHS * H;                    // 131072
    float* stats = t2 + N_GRAPHS * H;                   // 512 (two stat sets)
    int*   bsum  = (int*)(stats + 4 * H);               // 256

    hipMemsetAsync(cntO, 0, 2 * N_NODES * sizeof(int), stream);

    const int eb = (N_EDGES + 255) / 256;
    k_count<<<eb, 256, 0, stream>>>(edge_src, edge_dst, cntO, cntI, N_EDGES);
    k_blocksum<<<SCAN_BLOCKS, 256, 0, stream>>>(cntI, bsum, N_NODES);
    k_scanbsum<<<1, 256, 0, stream>>>(bsum, row_ptr + N_NODES, SCAN_BLOCKS);
    k_scatterscan<<<SCAN_BLOCKS, 256, 0, stream>>>(cntI, cntO, bsum, row_ptr, cursor, oi, ii, N_NODES);
    k_fill<<<eb, 256, 0, stream>>>(edge_src, edge_dst, cursor, col, N_EDGES);

    const int gb = (N_NODES * 64 + 255) / 256;
    const int tb = (N_NODES + TROWS - 1) / TROWS;

    // layer 1: gather straight from embedding table, transform -> bf16 h1
    k_gather_emb<<<gb, 256, 0, stream>>>(node_feat, emb, oi, row_ptr, col, bufA, N_NODES);
    k_transform<1><<<tb, 256, 0, stream>>>(bufA, ii, W1, b1, h1bf, N_NODES);
    // layer 2: gather bf16 h1, transform in-place -> f32 h2 in bufA
    k_gather_bf<<<gb, 256, 0, stream>>>(h1bf, oi, row_ptr, col, bufA, N_NODES);
    k_transform<0><<<tb, 256, 0, stream>>>(bufA, ii, W2, b2, bufA, N_NODES);

    // pooling
    k_pool<<<N_GRAPHS, 128, 0, stream>>>(bufA, graph_ids, hg, N_NODES);

    // MLP head (5 kernels)
    k_mlp1<<<N_GRAPHS, 128, 0, stream>>>(hg, e1_w, e1_b, t1);
    k_bnstat<<<H, 256, 0, stream>>>(t1, stats, N_GRAPHS);
    k_mlp2bn<<<N_GRAPHS, 128, 0, stream>>>(t1, stats, bn0_g, bn0_b, e2_w, e2_b, t2);
    k_bnstat<<<H, 256, 0, stream>>>(t2, stats + 2 * H, N_GRAPHS);
    k_head<<<N_GRAPHS, 128, 0, stream>>>(t2, stats + 2 * H, bn1_g, bn1_b,
                                         e3_w, e3_b, e4_w, e4_b, e5_w, e5_b, out);
}

// Round 4
// 308.765 us; speedup vs baseline: 1.4864x; 1.0985x over previous
//
#include <hip/hip_runtime.h>
#include <hip/hip_bf16.h>
#include <math.h>

#define N_NODES 50000
#define N_EDGES 600000
#define N_GRAPHS 1024
#define H 128
#define VOCAB 32
#define BN_EPS 1e-5f
#define SCAN_BLOCKS ((N_NODES + 255) / 256)   // 196

// ---------------- degree / CSR build ----------------

__global__ void k_count(const int* __restrict__ src, const int* __restrict__ dst,
                        int* __restrict__ cntO, int* __restrict__ cntI, int E) {
    int i = blockIdx.x * blockDim.x + threadIdx.x;
    if (i < E) {
        atomicAdd(&cntO[src[i]], 1);
        atomicAdd(&cntI[dst[i]], 1);
    }
}

__global__ void k_blocksum(const int* __restrict__ cnt, int* __restrict__ bsum, int n) {
    __shared__ int red[256];
    int i = blockIdx.x * 256 + threadIdx.x;
    red[threadIdx.x] = (i < n) ? cnt[i] : 0;
    __syncthreads();
    for (int off = 128; off > 0; off >>= 1) {
        if (threadIdx.x < off) red[threadIdx.x] += red[threadIdx.x + off];
        __syncthreads();
    }
    if (threadIdx.x == 0) bsum[blockIdx.x] = red[0];
}

__global__ void k_scanbsum(int* __restrict__ bsum, int* __restrict__ row_ptr_last, int nb) {
    __shared__ int sh[256];
    int t = threadIdx.x;
    int v = (t < nb) ? bsum[t] : 0;
    sh[t] = v;
    __syncthreads();
    for (int off = 1; off < 256; off <<= 1) {
        int u = (t >= off) ? sh[t - off] : 0;
        __syncthreads();
        sh[t] += u;
        __syncthreads();
    }
    if (t < nb) bsum[t] = sh[t] - v;            // exclusive
    if (t == nb - 1) *row_ptr_last = sh[t];      // grand total
}

// per-block exclusive scan + block offset -> row_ptr, cursor; also rsqrt norms
__global__ void k_scatterscan(const int* __restrict__ cntI, const int* __restrict__ cntO,
                              const int* __restrict__ bsum,
                              int* __restrict__ row_ptr, int* __restrict__ cursor,
                              float* __restrict__ oi, float* __restrict__ ii, int n) {
    __shared__ int sh[256];
    int i = blockIdx.x * 256 + threadIdx.x;
    int t = threadIdx.x;
    int v = (i < n) ? cntI[i] : 0;
    sh[t] = v;
    __syncthreads();
    for (int off = 1; off < 256; off <<= 1) {
        int u = (t >= off) ? sh[t - off] : 0;
        __syncthreads();
        sh[t] += u;
        __syncthreads();
    }
    if (i < n) {
        int ex = bsum[blockIdx.x] + sh[t] - v;
        row_ptr[i] = ex;
        cursor[i] = ex;
        ii[i] = rsqrtf(fmaxf((float)v, 1.f));
        oi[i] = rsqrtf(fmaxf((float)cntO[i], 1.f));
    }
}

__global__ void k_fill(const int* __restrict__ src, const int* __restrict__ dst,
                       int* __restrict__ cursor, int* __restrict__ col, int E) {
    int i = blockIdx.x * blockDim.x + threadIdx.x;
    if (i < E) {
        int p = atomicAdd(&cursor[dst[i]], 1);
        col[p] = src[i];
    }
}

// ---------------- node pipeline ----------------

// layer-1 gather via 32-bin histogram: agg[dst] = sum_v w[v] * emb[v]
// where w[v] = sum over in-edges with feat[src]==v of oi[src].
// 4 waves per block, one node per wave.
__global__ void k_gather_emb(const int* __restrict__ feat, const float* __restrict__ emb,
                             const float* __restrict__ oi,
                             const int* __restrict__ row_ptr, const int* __restrict__ col,
                             float* __restrict__ out, int n) {
    __shared__ float w[4][VOCAB];
    int wid = threadIdx.x >> 6;
    int lane = threadIdx.x & 63;
    int node = blockIdx.x * 4 + wid;   // n divisible by 4
    if (lane < VOCAB) w[wid][lane] = 0.f;
    __syncthreads();
    int beg = row_ptr[node];
    int end = row_ptr[node + 1];
    for (int e = beg + lane; e < end; e += 64) {
        int s = col[e];
        atomicAdd(&w[wid][feat[s]], oi[s]);
    }
    __syncthreads();
    float a0 = 0.f, a1 = 0.f;
    const float* erow = emb + lane * 2;
#pragma unroll
    for (int v = 0; v < VOCAB; ++v) {
        float wv = w[wid][v];
        float2 ev = *(const float2*)(erow + v * H);
        a0 += wv * ev.x;
        a1 += wv * ev.y;
    }
    *(float2*)(out + (size_t)node * H + lane * 2) = make_float2(a0, a1);
}

// layer-2 gather over bf16 pre-scaled features (oi folded in at store time),
// 4-wide padded batches for memory-level parallelism
__global__ void k_gather_bf(const __hip_bfloat16* __restrict__ h,
                            const int* __restrict__ row_ptr, const int* __restrict__ col,
                            float* __restrict__ out, int n) {
    int gid = blockIdx.x * blockDim.x + threadIdx.x;
    int node = gid >> 6;
    int lane = gid & 63;
    if (node >= n) return;
    int beg = row_ptr[node];
    int end = row_ptr[node + 1];
    int lo = lane * 2;
    float a0 = 0.f, a1 = 0.f;
    for (int e = beg; e < end; e += 4) {
        int e1 = (e + 1 < end) ? e + 1 : e;
        int e2 = (e + 2 < end) ? e + 2 : e;
        int e3 = (e + 3 < end) ? e + 3 : e;
        int s0 = col[e], s1 = col[e1], s2 = col[e2], s3 = col[e3];
        __hip_bfloat162 v0 = *(const __hip_bfloat162*)(h + (size_t)s0 * H + lo);
        __hip_bfloat162 v1 = *(const __hip_bfloat162*)(h + (size_t)s1 * H + lo);
        __hip_bfloat162 v2 = *(const __hip_bfloat162*)(h + (size_t)s2 * H + lo);
        __hip_bfloat162 v3 = *(const __hip_bfloat162*)(h + (size_t)s3 * H + lo);
        float m1 = (e + 1 < end) ? 1.f : 0.f;
        float m2 = (e + 2 < end) ? 1.f : 0.f;
        float m3 = (e + 3 < end) ? 1.f : 0.f;
        float2 f0 = __bfloat1622float2(v0);
        float2 f1 = __bfloat1622float2(v1);
        float2 f2 = __bfloat1622float2(v2);
        float2 f3 = __bfloat1622float2(v3);
        a0 += f0.x + m1 * f1.x + m2 * f2.x + m3 * f3.x;
        a1 += f0.y + m1 * f1.y + m2 * f2.y + m3 * f3.y;
    }
    *(float2*)(out + (size_t)node * H + lane * 2) = make_float2(a0, a1);
}

// out[n][j] = relu( (in[n][:]*ii[n]) @ W + b[j] ); 16-row tile, 256 threads.
// BF16OUT=1: write bf16 scaled by oscale[node] (pre-fold out-norm for next gather).
#define TROWS 16
template <int BF16OUT>
__global__ void k_transform(const float* in, const float* __restrict__ ii,
                            const float* __restrict__ oscale,
                            const float* __restrict__ W, const float* __restrict__ b,
                            void* outp, int n) {
    __shared__ float At[TROWS][H];
    int block0 = blockIdx.x * TROWS;
    int tid = threadIdx.x;
    for (int i = tid; i < TROWS * H; i += 256) {
        int r = i >> 7, c = i & 127;
        int node = block0 + r;
        At[r][c] = (node < n) ? in[(size_t)node * H + c] * ii[node] : 0.f;
    }
    __syncthreads();
    int j = tid & 127;
    int ty = tid >> 7;  // 0..1, each handles 8 rows
    float acc[8];
#pragma unroll
    for (int r = 0; r < 8; ++r) acc[r] = 0.f;
    for (int k = 0; k < H; ++k) {
        float w = W[k * H + j];
#pragma unroll
        for (int r = 0; r < 8; ++r) acc[r] += At[ty * 8 + r][k] * w;
    }
    float bj = b[j];
#pragma unroll
    for (int r = 0; r < 8; ++r) {
        int node = block0 + ty * 8 + r;
        if (node < n) {
            float v = fmaxf(acc[r] + bj, 0.f);
            if (BF16OUT)
                ((__hip_bfloat16*)outp)[(size_t)node * H + j] =
                    __float2bfloat16(v * oscale[node]);
            else
                ((float*)outp)[(size_t)node * H + j] = v;
        }
    }
}

// per-graph mean via binary search over sorted graph_ids; block per graph, 128 threads
__global__ void k_pool(const float* __restrict__ h, const int* __restrict__ gid,
                       float* __restrict__ hg, int n) {
    int g = blockIdx.x;
    __shared__ int sh[2];
    if (threadIdx.x == 0) {
        int lo = 0, hi = n;
        while (lo < hi) { int m = (lo + hi) >> 1; if (gid[m] < g) lo = m + 1; else hi = m; }
        sh[0] = lo;
        int lo2 = lo, hi2 = n;
        while (lo2 < hi2) { int m = (lo2 + hi2) >> 1; if (gid[m] < g + 1) lo2 = m + 1; else hi2 = m; }
        sh[1] = lo2;
    }
    __syncthreads();
    int beg = sh[0], end = sh[1];
    int c = threadIdx.x;
    float s = 0.f;
    for (int i = beg; i < end; ++i) s += h[(size_t)i * H + c];
    float cnt = (float)(end - beg);
    hg[g * H + c] = s / fmaxf(cnt, 1.f);
}

// ---------------- MLP head ----------------

__global__ void k_mlp1(const float* __restrict__ in, const float* __restrict__ W,
                       const float* __restrict__ b, float* __restrict__ out) {
    __shared__ float ld[128];
    int g = blockIdx.x;
    int t = threadIdx.x;
    ld[t] = in[g * H + t];
    __syncthreads();
    float acc = b[t];
    for (int k = 0; k < H; ++k) acc += ld[k] * W[k * H + t];
    out[g * H + t] = acc;
}

__global__ void k_bnstat(const float* __restrict__ x, float* __restrict__ stats, int G) {
    int c = blockIdx.x;
    float s = 0.f, s2 = 0.f;
    for (int g = threadIdx.x; g < G; g += blockDim.x) {
        float v = x[g * H + c];
        s += v; s2 += v * v;
    }
    __shared__ float rs[256], rs2[256];
    rs[threadIdx.x] = s; rs2[threadIdx.x] = s2;
    __syncthreads();
    for (int off = 128; off > 0; off >>= 1) {
        if (threadIdx.x < off) { rs[threadIdx.x] += rs[threadIdx.x + off]; rs2[threadIdx.x] += rs2[threadIdx.x + off]; }
        __syncthreads();
    }
    if (threadIdx.x == 0) {
        float mu = rs[0] / G;
        stats[c] = mu;
        stats[H + c] = rs2[0] / G - mu * mu;
    }
}

__global__ void k_mlp2bn(const float* __restrict__ t1, const float* __restrict__ stats,
                         const float* __restrict__ gam, const float* __restrict__ bet,
                         const float* __restrict__ W, const float* __restrict__ bias,
                         float* __restrict__ t2) {
    __shared__ float x[128];
    int g = blockIdx.x, t = threadIdx.x;
    float v = t1[g * H + t];
    v = (v - stats[t]) * rsqrtf(stats[H + t] + BN_EPS) * gam[t] + bet[t];
    x[t] = (v >= 0.f) ? v : 0.05f * v;
    __syncthreads();
    float acc = bias[t];
    for (int k = 0; k < H; ++k) acc += x[k] * W[k * H + t];
    t2[g * H + t] = acc;
}

__global__ void k_head(const float* __restrict__ t2, const float* __restrict__ stats,
                       const float* __restrict__ gam, const float* __restrict__ bet,
                       const float* __restrict__ e3w, const float* __restrict__ e3b,
                       const float* __restrict__ e4w, const float* __restrict__ e4b,
                       const float* __restrict__ e5w, const float* __restrict__ e5b,
                       float* __restrict__ out) {
    __shared__ float x[128], h3[64], h4[32];
    int g = blockIdx.x, t = threadIdx.x;
    float v = t2[g * H + t];
    v = (v - stats[t]) * rsqrtf(stats[H + t] + BN_EPS) * gam[t] + bet[t];
    x[t] = (v >= 0.f) ? v : 0.05f * v;
    __syncthreads();
    if (t < 64) {
        float a = e3b[t];
        for (int k = 0; k < 128; ++k) a += x[k] * e3w[k * 64 + t];
        h3[t] = (a >= 0.f) ? a : 0.1f * a;
    }
    __syncthreads();
    if (t < 32) {
        float a = e4b[t];
        for (int k = 0; k < 64; ++k) a += h3[k] * e4w[k * 32 + t];
        h4[t] = (a >= 0.f) ? a : 0.1f * a;
    }
    __syncthreads();
    if (t == 0) {
        float y0 = e5b[0], y1 = e5b[1];
        for (int k = 0; k < 32; ++k) {
            y0 += h4[k] * e5w[2 * k];
            y1 += h4[k] * e5w[2 * k + 1];
        }
        float m = fmaxf(y0, y1);
        float l = m + logf(expf(y0 - m) + expf(y1 - m));
        out[2 * g] = y0 - l;
        out[2 * g + 1] = y1 - l;
    }
}

extern "C" void kernel_launch(void* const* d_in, const int* in_sizes, int n_in,
                              void* d_out, int out_size, void* d_ws, size_t ws_size,
                              hipStream_t stream) {
    const int*   node_feat = (const int*)d_in[0];
    const int*   edge_src  = (const int*)d_in[1];
    const int*   edge_dst  = (const int*)d_in[2];
    const int*   graph_ids = (const int*)d_in[3];
    const float* emb  = (const float*)d_in[4];
    const float* W1   = (const float*)d_in[5];
    const float* b1   = (const float*)d_in[6];
    const float* W2   = (const float*)d_in[7];
    const float* b2   = (const float*)d_in[8];
    const float* e1_w = (const float*)d_in[9];
    const float* e1_b = (const float*)d_in[10];
    const float* e2_w = (const float*)d_in[11];
    const float* e2_b = (const float*)d_in[12];
    const float* e3_w = (const float*)d_in[13];
    const float* e3_b = (const float*)d_in[14];
    const float* e4_w = (const float*)d_in[15];
    const float* e4_b = (const float*)d_in[16];
    const float* e5_w = (const float*)d_in[17];
    const float* e5_b = (const float*)d_in[18];
    const float* bn0_g = (const float*)d_in[19];
    const float* bn0_b = (const float*)d_in[20];
    const float* bn1_g = (const float*)d_in[21];
    const float* bn1_b = (const float*)d_in[22];
    float* out = (float*)d_out;

    // workspace layout (floats)
    float* ws = (float*)d_ws;
    float* bufA = ws;                                   // N*H f32 (agg / h2, in-place)
    __hip_bfloat16* h1bf = (__hip_bfloat16*)(bufA + (size_t)N_NODES * H);  // N*H bf16
    float* after = (float*)(h1bf + (size_t)N_NODES * H);
    int*   cntO = (int*)after;                          // 50000
    int*   cntI = cntO + N_NODES;                       // 50000
    float* oi   = (float*)(cntI + N_NODES);
    float* ii   = oi + N_NODES;
    int*   row_ptr = (int*)(ii + N_NODES);              // 50001 -> pad 50048
    int*   cursor  = row_ptr + 50048;                   // 50000 -> pad 50048
    int*   col  = cursor + 50048;                       // 600000
    float* hg   = (float*)(col + N_EDGES);              // 131072
    float* t1   = hg + N_GRAPHS * H;                    // 131072
    float* t2   = t1 + N_GRAPHS * H;                    // 131072
    float* stats = t2 + N_GRAPHS * H;                   // 512 (two stat sets)
    int*   bsum  = (int*)(stats + 4 * H);               // 256

    hipMemsetAsync(cntO, 0, 2 * N_NODES * sizeof(int), stream);

    const int eb = (N_EDGES + 255) / 256;
    k_count<<<eb, 256, 0, stream>>>(edge_src, edge_dst, cntO, cntI, N_EDGES);
    k_blocksum<<<SCAN_BLOCKS, 256, 0, stream>>>(cntI, bsum, N_NODES);
    k_scanbsum<<<1, 256, 0, stream>>>(bsum, row_ptr + N_NODES, SCAN_BLOCKS);
    k_scatterscan<<<SCAN_BLOCKS, 256, 0, stream>>>(cntI, cntO, bsum, row_ptr, cursor, oi, ii, N_NODES);
    k_fill<<<eb, 256, 0, stream>>>(edge_src, edge_dst, cursor, col, N_EDGES);

    const int gb = (N_NODES * 64 + 255) / 256;
    const int tb = (N_NODES + TROWS - 1) / TROWS;

    // layer 1: histogram gather from 16KB emb table, transform -> bf16 h1 (pre-scaled by oi)
    k_gather_emb<<<N_NODES / 4, 256, 0, stream>>>(node_feat, emb, oi, row_ptr, col, bufA, N_NODES);
    k_transform<1><<<tb, 256, 0, stream>>>(bufA, ii, oi, W1, b1, h1bf, N_NODES);
    // layer 2: batched gather of pre-scaled bf16 h1, transform in-place -> f32 h2
    k_gather_bf<<<gb, 256, 0, stream>>>(h1bf, row_ptr, col, bufA, N_NODES);
    k_transform<0><<<tb, 256, 0, stream>>>(bufA, ii, nullptr, W2, b2, bufA, N_NODES);

    // pooling
    k_pool<<<N_GRAPHS, 128, 0, stream>>>(bufA, graph_ids, hg, N_NODES);

    // MLP head (5 kernels)
    k_mlp1<<<N_GRAPHS, 128, 0, stream>>>(hg, e1_w, e1_b, t1);
    k_bnstat<<<H, 256, 0, stream>>>(t1, stats, N_GRAPHS);
    k_mlp2bn<<<N_GRAPHS, 128, 0, stream>>>(t1, stats, bn0_g, bn0_b, e2_w, e2_b, t2);
    k_bnstat<<<H, 256, 0, stream>>>(t2, stats + 2 * H, N_GRAPHS);
    k_head<<<N_GRAPHS, 128, 0, stream>>>(t2, stats + 2 * H, bn1_g, bn1_b,
                                         e3_w, e3_b, e4_w, e4_b, e5_w, e5_b, out);
}

// Round 5
// 301.878 us; speedup vs baseline: 1.5203x; 1.0228x over previous
//
#include <hip/hip_runtime.h>
#include <hip/hip_bf16.h>
#include <math.h>

#define N_NODES 50000
#define N_EDGES 600000
#define N_GRAPHS 1024
#define H 128
#define VOCAB 32
#define BN_EPS 1e-5f
#define SCAN_BLOCKS ((N_NODES + 255) / 256)   // 196

// ---------------- degree / CSR build ----------------

__global__ void k_count(const int* __restrict__ src, const int* __restrict__ dst,
                        int* __restrict__ cntO, int* __restrict__ cntI, int E) {
    int i = blockIdx.x * blockDim.x + threadIdx.x;
    if (i < E) {
        atomicAdd(&cntO[src[i]], 1);
        atomicAdd(&cntI[dst[i]], 1);
    }
}

__global__ void k_blocksum(const int* __restrict__ cnt, int* __restrict__ bsum, int n) {
    __shared__ int red[256];
    int i = blockIdx.x * 256 + threadIdx.x;
    red[threadIdx.x] = (i < n) ? cnt[i] : 0;
    __syncthreads();
    for (int off = 128; off > 0; off >>= 1) {
        if (threadIdx.x < off) red[threadIdx.x] += red[threadIdx.x + off];
        __syncthreads();
    }
    if (threadIdx.x == 0) bsum[blockIdx.x] = red[0];
}

__global__ void k_scanbsum(int* __restrict__ bsum, int* __restrict__ row_ptr_last, int nb) {
    __shared__ int sh[256];
    int t = threadIdx.x;
    int v = (t < nb) ? bsum[t] : 0;
    sh[t] = v;
    __syncthreads();
    for (int off = 1; off < 256; off <<= 1) {
        int u = (t >= off) ? sh[t - off] : 0;
        __syncthreads();
        sh[t] += u;
        __syncthreads();
    }
    if (t < nb) bsum[t] = sh[t] - v;            // exclusive
    if (t == nb - 1) *row_ptr_last = sh[t];      // grand total
}

// per-block exclusive scan + block offset -> row_ptr, cursor; also rsqrt norms
__global__ void k_scatterscan(const int* __restrict__ cntI, const int* __restrict__ cntO,
                              const int* __restrict__ bsum,
                              int* __restrict__ row_ptr, int* __restrict__ cursor,
                              float* __restrict__ oi, float* __restrict__ ii, int n) {
    __shared__ int sh[256];
    int i = blockIdx.x * 256 + threadIdx.x;
    int t = threadIdx.x;
    int v = (i < n) ? cntI[i] : 0;
    sh[t] = v;
    __syncthreads();
    for (int off = 1; off < 256; off <<= 1) {
        int u = (t >= off) ? sh[t - off] : 0;
        __syncthreads();
        sh[t] += u;
        __syncthreads();
    }
    if (i < n) {
        int ex = bsum[blockIdx.x] + sh[t] - v;
        row_ptr[i] = ex;
        cursor[i] = ex;
        ii[i] = rsqrtf(fmaxf((float)v, 1.f));
        oi[i] = rsqrtf(fmaxf((float)cntO[i], 1.f));
    }
}

__global__ void k_fill(const int* __restrict__ src, const int* __restrict__ dst,
                       int* __restrict__ cursor, int* __restrict__ col, int E) {
    int i = blockIdx.x * blockDim.x + threadIdx.x;
    if (i < E) {
        int p = atomicAdd(&cursor[dst[i]], 1);
        col[p] = src[i];
    }
}

// ---------------- layer 1 in vocab space ----------------

// per-edge vocab histogram: w[dst][feat[src]] += oi[src]  (6.4MB, L2-resident)
__global__ void k_hist(const int* __restrict__ src, const int* __restrict__ dst,
                       const int* __restrict__ feat, const float* __restrict__ oi,
                       float* __restrict__ w, int E) {
    int i = blockIdx.x * blockDim.x + threadIdx.x;
    if (i < E) {
        int s = src[i];
        atomicAdd(&w[(size_t)dst[i] * VOCAB + feat[s]], oi[s]);
    }
}

// emb1 = emb @ W1  (32 x 128)
__global__ void k_emb1(const float* __restrict__ emb, const float* __restrict__ W1,
                       float* __restrict__ emb1) {
    int v = blockIdx.x;
    int j = threadIdx.x;
    float acc = 0.f;
    for (int k = 0; k < H; ++k) acc += emb[v * H + k] * W1[k * H + j];
    emb1[v * H + j] = acc;
}

// h1[node][j] = relu( ii[node] * (w[node][:] @ emb1[:][j]) + b1[j] ) * oi[node], bf16
// 2 nodes per 256-thread block; w-row loads are wave-uniform (scalar), emb1 L1-hot.
__global__ void k_h1(const float* __restrict__ w, const float* __restrict__ emb1,
                     const float* __restrict__ ii, const float* __restrict__ oi,
                     const float* __restrict__ b1, __hip_bfloat16* __restrict__ h1) {
    int node = blockIdx.x * 2 + (threadIdx.x >> 7);
    int j = threadIdx.x & 127;
    const float* wr = w + (size_t)node * VOCAB;
    float acc = 0.f;
#pragma unroll
    for (int v = 0; v < VOCAB; ++v) acc += wr[v] * emb1[v * H + j];
    float val = fmaxf(acc * ii[node] + b1[j], 0.f);
    h1[(size_t)node * H + j] = __float2bfloat16(val * oi[node]);
}

// ---------------- layer 2 ----------------

// gather over bf16 pre-scaled features, 4-wide padded batches for MLP
__global__ void k_gather_bf(const __hip_bfloat16* __restrict__ h,
                            const int* __restrict__ row_ptr, const int* __restrict__ col,
                            float* __restrict__ out, int n) {
    int gid = blockIdx.x * blockDim.x + threadIdx.x;
    int node = gid >> 6;
    int lane = gid & 63;
    if (node >= n) return;
    int beg = row_ptr[node];
    int end = row_ptr[node + 1];
    int lo = lane * 2;
    float a0 = 0.f, a1 = 0.f;
    for (int e = beg; e < end; e += 4) {
        int e1 = (e + 1 < end) ? e + 1 : e;
        int e2 = (e + 2 < end) ? e + 2 : e;
        int e3 = (e + 3 < end) ? e + 3 : e;
        int s0 = col[e], s1 = col[e1], s2 = col[e2], s3 = col[e3];
        __hip_bfloat162 v0 = *(const __hip_bfloat162*)(h + (size_t)s0 * H + lo);
        __hip_bfloat162 v1 = *(const __hip_bfloat162*)(h + (size_t)s1 * H + lo);
        __hip_bfloat162 v2 = *(const __hip_bfloat162*)(h + (size_t)s2 * H + lo);
        __hip_bfloat162 v3 = *(const __hip_bfloat162*)(h + (size_t)s3 * H + lo);
        float m1 = (e + 1 < end) ? 1.f : 0.f;
        float m2 = (e + 2 < end) ? 1.f : 0.f;
        float m3 = (e + 3 < end) ? 1.f : 0.f;
        float2 f0 = __bfloat1622float2(v0);
        float2 f1 = __bfloat1622float2(v1);
        float2 f2 = __bfloat1622float2(v2);
        float2 f3 = __bfloat1622float2(v3);
        a0 += f0.x + m1 * f1.x + m2 * f2.x + m3 * f3.x;
        a1 += f0.y + m1 * f1.y + m2 * f2.y + m3 * f3.y;
    }
    *(float2*)(out + (size_t)node * H + lane * 2) = make_float2(a0, a1);
}

// out[n][j] = relu( (in[n][:]*ii[n]) @ W + b[j] ); 16-row tile, 256 threads. In-place safe.
#define TROWS 16
__global__ void k_transform(const float* in, const float* __restrict__ ii,
                            const float* __restrict__ W, const float* __restrict__ b,
                            float* __restrict__ outp, int n) {
    __shared__ float At[TROWS][H];
    int block0 = blockIdx.x * TROWS;
    int tid = threadIdx.x;
    for (int i = tid; i < TROWS * H; i += 256) {
        int r = i >> 7, c = i & 127;
        int node = block0 + r;
        At[r][c] = (node < n) ? in[(size_t)node * H + c] * ii[node] : 0.f;
    }
    __syncthreads();
    int j = tid & 127;
    int ty = tid >> 7;  // 0..1, each handles 8 rows
    float acc[8];
#pragma unroll
    for (int r = 0; r < 8; ++r) acc[r] = 0.f;
    for (int k = 0; k < H; ++k) {
        float w = W[k * H + j];
#pragma unroll
        for (int r = 0; r < 8; ++r) acc[r] += At[ty * 8 + r][k] * w;
    }
    float bj = b[j];
#pragma unroll
    for (int r = 0; r < 8; ++r) {
        int node = block0 + ty * 8 + r;
        if (node < n) outp[(size_t)node * H + j] = fmaxf(acc[r] + bj, 0.f);
    }
}

// per-graph mean via binary search over sorted graph_ids; block per graph, 128 threads
__global__ void k_pool(const float* __restrict__ h, const int* __restrict__ gid,
                       float* __restrict__ hg, int n) {
    int g = blockIdx.x;
    __shared__ int sh[2];
    if (threadIdx.x == 0) {
        int lo = 0, hi = n;
        while (lo < hi) { int m = (lo + hi) >> 1; if (gid[m] < g) lo = m + 1; else hi = m; }
        sh[0] = lo;
        int lo2 = lo, hi2 = n;
        while (lo2 < hi2) { int m = (lo2 + hi2) >> 1; if (gid[m] < g + 1) lo2 = m + 1; else hi2 = m; }
        sh[1] = lo2;
    }
    __syncthreads();
    int beg = sh[0], end = sh[1];
    int c = threadIdx.x;
    float s = 0.f;
    for (int i = beg; i < end; ++i) s += h[(size_t)i * H + c];
    float cnt = (float)(end - beg);
    hg[g * H + c] = s / fmaxf(cnt, 1.f);
}

// ---------------- MLP head ----------------

__global__ void k_mlp1(const float* __restrict__ in, const float* __restrict__ W,
                       const float* __restrict__ b, float* __restrict__ out) {
    __shared__ float ld[128];
    int g = blockIdx.x;
    int t = threadIdx.x;
    ld[t] = in[g * H + t];
    __syncthreads();
    float acc = b[t];
    for (int k = 0; k < H; ++k) acc += ld[k] * W[k * H + t];
    out[g * H + t] = acc;
}

__global__ void k_bnstat(const float* __restrict__ x, float* __restrict__ stats, int G) {
    int c = blockIdx.x;
    float s = 0.f, s2 = 0.f;
    for (int g = threadIdx.x; g < G; g += blockDim.x) {
        float v = x[g * H + c];
        s += v; s2 += v * v;
    }
    __shared__ float rs[256], rs2[256];
    rs[threadIdx.x] = s; rs2[threadIdx.x] = s2;
    __syncthreads();
    for (int off = 128; off > 0; off >>= 1) {
        if (threadIdx.x < off) { rs[threadIdx.x] += rs[threadIdx.x + off]; rs2[threadIdx.x] += rs2[threadIdx.x + off]; }
        __syncthreads();
    }
    if (threadIdx.x == 0) {
        float mu = rs[0] / G;
        stats[c] = mu;
        stats[H + c] = rs2[0] / G - mu * mu;
    }
}

__global__ void k_mlp2bn(const float* __restrict__ t1, const float* __restrict__ stats,
                         const float* __restrict__ gam, const float* __restrict__ bet,
                         const float* __restrict__ W, const float* __restrict__ bias,
                         float* __restrict__ t2) {
    __shared__ float x[128];
    int g = blockIdx.x, t = threadIdx.x;
    float v = t1[g * H + t];
    v = (v - stats[t]) * rsqrtf(stats[H + t] + BN_EPS) * gam[t] + bet[t];
    x[t] = (v >= 0.f) ? v : 0.05f * v;
    __syncthreads();
    float acc = bias[t];
    for (int k = 0; k < H; ++k) acc += x[k] * W[k * H + t];
    t2[g * H + t] = acc;
}

__global__ void k_head(const float* __restrict__ t2, const float* __restrict__ stats,
                       const float* __restrict__ gam, const float* __restrict__ bet,
                       const float* __restrict__ e3w, const float* __restrict__ e3b,
                       const float* __restrict__ e4w, const float* __restrict__ e4b,
                       const float* __restrict__ e5w, const float* __restrict__ e5b,
                       float* __restrict__ out) {
    __shared__ float x[128], h3[64], h4[32];
    int g = blockIdx.x, t = threadIdx.x;
    float v = t2[g * H + t];
    v = (v - stats[t]) * rsqrtf(stats[H + t] + BN_EPS) * gam[t] + bet[t];
    x[t] = (v >= 0.f) ? v : 0.05f * v;
    __syncthreads();
    if (t < 64) {
        float a = e3b[t];
        for (int k = 0; k < 128; ++k) a += x[k] * e3w[k * 64 + t];
        h3[t] = (a >= 0.f) ? a : 0.1f * a;
    }
    __syncthreads();
    if (t < 32) {
        float a = e4b[t];
        for (int k = 0; k < 64; ++k) a += h3[k] * e4w[k * 32 + t];
        h4[t] = (a >= 0.f) ? a : 0.1f * a;
    }
    __syncthreads();
    if (t == 0) {
        float y0 = e5b[0], y1 = e5b[1];
        for (int k = 0; k < 32; ++k) {
            y0 += h4[k] * e5w[2 * k];
            y1 += h4[k] * e5w[2 * k + 1];
        }
        float m = fmaxf(y0, y1);
        float l = m + logf(expf(y0 - m) + expf(y1 - m));
        out[2 * g] = y0 - l;
        out[2 * g + 1] = y1 - l;
    }
}

extern "C" void kernel_launch(void* const* d_in, const int* in_sizes, int n_in,
                              void* d_out, int out_size, void* d_ws, size_t ws_size,
                              hipStream_t stream) {
    const int*   node_feat = (const int*)d_in[0];
    const int*   edge_src  = (const int*)d_in[1];
    const int*   edge_dst  = (const int*)d_in[2];
    const int*   graph_ids = (const int*)d_in[3];
    const float* emb  = (const float*)d_in[4];
    const float* W1   = (const float*)d_in[5];
    const float* b1   = (const float*)d_in[6];
    const float* W2   = (const float*)d_in[7];
    const float* b2   = (const float*)d_in[8];
    const float* e1_w = (const float*)d_in[9];
    const float* e1_b = (const float*)d_in[10];
    const float* e2_w = (const float*)d_in[11];
    const float* e2_b = (const float*)d_in[12];
    const float* e3_w = (const float*)d_in[13];
    const float* e3_b = (const float*)d_in[14];
    const float* e4_w = (const float*)d_in[15];
    const float* e4_b = (const float*)d_in[16];
    const float* e5_w = (const float*)d_in[17];
    const float* e5_b = (const float*)d_in[18];
    const float* bn0_g = (const float*)d_in[19];
    const float* bn0_b = (const float*)d_in[20];
    const float* bn1_g = (const float*)d_in[21];
    const float* bn1_b = (const float*)d_in[22];
    float* out = (float*)d_out;

    // workspace layout (floats)
    float* ws = (float*)d_ws;
    float* bufA = ws;                                   // N*H f32 (agg2 / h2, in-place)
    __hip_bfloat16* h1bf = (__hip_bfloat16*)(bufA + (size_t)N_NODES * H);  // N*H bf16
    float* after = (float*)(h1bf + (size_t)N_NODES * H);
    int*   cntO = (int*)after;                          // 50000
    int*   cntI = cntO + N_NODES;                       // 50000
    float* w    = (float*)(cntI + N_NODES);             // N*32 (contiguous w/ counters for one memset)
    float* oi   = w + (size_t)N_NODES * VOCAB;
    float* ii   = oi + N_NODES;
    int*   row_ptr = (int*)(ii + N_NODES);              // 50001 -> pad 50048
    int*   cursor  = row_ptr + 50048;                   // 50000 -> pad 50048
    int*   col  = cursor + 50048;                       // 600000
    float* hg   = (float*)(col + N_EDGES);              // 131072
    float* t1   = hg + N_GRAPHS * H;                    // 131072
    float* t2   = t1 + N_GRAPHS * H;                    // 131072
    float* stats = t2 + N_GRAPHS * H;                   // 512 (two stat sets)
    int*   bsum  = (int*)(stats + 4 * H);               // 256
    float* emb1  = (float*)(bsum + 256);                // 4096

    // one memset covers cntO, cntI, w (contiguous)
    hipMemsetAsync(cntO, 0, (2 * N_NODES + N_NODES * VOCAB) * sizeof(int), stream);

    const int eb = (N_EDGES + 255) / 256;
    k_count<<<eb, 256, 0, stream>>>(edge_src, edge_dst, cntO, cntI, N_EDGES);
    k_blocksum<<<SCAN_BLOCKS, 256, 0, stream>>>(cntI, bsum, N_NODES);
    k_scanbsum<<<1, 256, 0, stream>>>(bsum, row_ptr + N_NODES, SCAN_BLOCKS);
    k_scatterscan<<<SCAN_BLOCKS, 256, 0, stream>>>(cntI, cntO, bsum, row_ptr, cursor, oi, ii, N_NODES);
    k_fill<<<eb, 256, 0, stream>>>(edge_src, edge_dst, cursor, col, N_EDGES);

    // layer 1 (vocab space): hist -> emb1 -> h1 (bf16, pre-scaled by oi)
    k_emb1<<<VOCAB, 128, 0, stream>>>(emb, W1, emb1);
    k_hist<<<eb, 256, 0, stream>>>(edge_src, edge_dst, node_feat, oi, w, N_EDGES);
    k_h1<<<N_NODES / 2, 256, 0, stream>>>(w, emb1, ii, oi, b1, h1bf);

    // layer 2: batched gather of pre-scaled bf16 h1, transform in-place -> f32 h2
    const int gb = (N_NODES * 64 + 255) / 256;
    const int tb = (N_NODES + TROWS - 1) / TROWS;
    k_gather_bf<<<gb, 256, 0, stream>>>(h1bf, row_ptr, col, bufA, N_NODES);
    k_transform<<<tb, 256, 0, stream>>>(bufA, ii, W2, b2, bufA, N_NODES);

    // pooling
    k_pool<<<N_GRAPHS, 128, 0, stream>>>(bufA, graph_ids, hg, N_NODES);

    // MLP head (5 kernels)
    k_mlp1<<<N_GRAPHS, 128, 0, stream>>>(hg, e1_w, e1_b, t1);
    k_bnstat<<<H, 256, 0, stream>>>(t1, stats, N_GRAPHS);
    k_mlp2bn<<<N_GRAPHS, 128, 0, stream>>>(t1, stats, bn0_g, bn0_b, e2_w, e2_b, t2);
    k_bnstat<<<H, 256, 0, stream>>>(t2, stats + 2 * H, N_GRAPHS);
    k_head<<<N_GRAPHS, 128, 0, stream>>>(t2, stats + 2 * H, bn1_g, bn1_b,
                                         e3_w, e3_b, e4_w, e4_b, e5_w, e5_b, out);
}

// Round 6
// 271.520 us; speedup vs baseline: 1.6903x; 1.1118x over previous
//
#include <hip/hip_runtime.h>
#include <hip/hip_bf16.h>
#include <math.h>

#define N_NODES 50000
#define N_EDGES 600000
#define N_GRAPHS 1024
#define H 128
#define VOCAB 32
#define BN_EPS 1e-5f
#define SCAN_BLOCKS ((N_NODES + 255) / 256)   // 196
#define H1_NODES 64

// ---------------- degree / CSR build ----------------

__global__ void k_count(const int* __restrict__ src, const int* __restrict__ dst,
                        int* __restrict__ cntO, int* __restrict__ cntI, int E) {
    int i = blockIdx.x * blockDim.x + threadIdx.x;
    if (i < E) {
        atomicAdd(&cntO[src[i]], 1);
        atomicAdd(&cntI[dst[i]], 1);
    }
}

__global__ void k_blocksum(const int* __restrict__ cnt, int* __restrict__ bsum, int n) {
    __shared__ int red[256];
    int i = blockIdx.x * 256 + threadIdx.x;
    red[threadIdx.x] = (i < n) ? cnt[i] : 0;
    __syncthreads();
    for (int off = 128; off > 0; off >>= 1) {
        if (threadIdx.x < off) red[threadIdx.x] += red[threadIdx.x + off];
        __syncthreads();
    }
    if (threadIdx.x == 0) bsum[blockIdx.x] = red[0];
}

__global__ void k_scanbsum(int* __restrict__ bsum, int* __restrict__ row_ptr_last, int nb) {
    __shared__ int sh[256];
    int t = threadIdx.x;
    int v = (t < nb) ? bsum[t] : 0;
    sh[t] = v;
    __syncthreads();
    for (int off = 1; off < 256; off <<= 1) {
        int u = (t >= off) ? sh[t - off] : 0;
        __syncthreads();
        sh[t] += u;
        __syncthreads();
    }
    if (t < nb) bsum[t] = sh[t] - v;            // exclusive
    if (t == nb - 1) *row_ptr_last = sh[t];      // grand total
}

// per-block exclusive scan + block offset -> row_ptr, cursor; also rsqrt norms
__global__ void k_scatterscan(const int* __restrict__ cntI, const int* __restrict__ cntO,
                              const int* __restrict__ bsum,
                              int* __restrict__ row_ptr, int* __restrict__ cursor,
                              float* __restrict__ oi, float* __restrict__ ii, int n) {
    __shared__ int sh[256];
    int i = blockIdx.x * 256 + threadIdx.x;
    int t = threadIdx.x;
    int v = (i < n) ? cntI[i] : 0;
    sh[t] = v;
    __syncthreads();
    for (int off = 1; off < 256; off <<= 1) {
        int u = (t >= off) ? sh[t - off] : 0;
        __syncthreads();
        sh[t] += u;
        __syncthreads();
    }
    if (i < n) {
        int ex = bsum[blockIdx.x] + sh[t] - v;
        row_ptr[i] = ex;
        cursor[i] = ex;
        ii[i] = rsqrtf(fmaxf((float)v, 1.f));
        oi[i] = rsqrtf(fmaxf((float)cntO[i], 1.f));
    }
}

__global__ void k_fill(const int* __restrict__ src, const int* __restrict__ dst,
                       int* __restrict__ cursor, int* __restrict__ col, int E) {
    int i = blockIdx.x * blockDim.x + threadIdx.x;
    if (i < E) {
        int p = atomicAdd(&cursor[dst[i]], 1);
        col[p] = src[i];
    }
}

// ---------------- layer 1 in vocab space ----------------

// per-edge vocab histogram: w[dst][feat[src]] += oi[src]  (6.4MB, L2-resident)
__global__ void k_hist(const int* __restrict__ src, const int* __restrict__ dst,
                       const int* __restrict__ feat, const float* __restrict__ oi,
                       float* __restrict__ w, int E) {
    int i = blockIdx.x * blockDim.x + threadIdx.x;
    if (i < E) {
        int s = src[i];
        atomicAdd(&w[(size_t)dst[i] * VOCAB + feat[s]], oi[s]);
    }
}

// emb1 = emb @ W1  (32 x 128)
__global__ void k_emb1(const float* __restrict__ emb, const float* __restrict__ W1,
                       float* __restrict__ emb1) {
    int v = blockIdx.x;
    int j = threadIdx.x;
    float acc = 0.f;
    for (int k = 0; k < H; ++k) acc += emb[v * H + k] * W1[k * H + j];
    emb1[v * H + j] = acc;
}

// h1[node][j] = relu( ii[node]*(w[node][:] @ emb1[:][j]) + b1[j] ) * oi[node], bf16.
// emb1 column j lives in 32 VGPRs; 64 nodes' w rows + ii/oi staged in LDS.
__global__ void k_h1(const float* __restrict__ w, const float* __restrict__ emb1,
                     const float* __restrict__ ii, const float* __restrict__ oi,
                     const float* __restrict__ b1, __hip_bfloat16* __restrict__ h1, int n) {
    __shared__ float wl[H1_NODES * VOCAB];   // 8 KB
    __shared__ float sii[H1_NODES], soi[H1_NODES];
    int tid = threadIdx.x;
    int j = tid & 127;
    int g = tid >> 7;          // 0..1, each group handles 32 nodes
    // emb1 column j -> registers (coalesced loads, done once)
    float ev[VOCAB];
#pragma unroll
    for (int v = 0; v < VOCAB; ++v) ev[v] = emb1[v * H + j];
    float bj = b1[j];

    int node0 = blockIdx.x * H1_NODES;
    int nn = min(H1_NODES, n - node0);       // nodes in this block
    // cooperative stage: nn*32 floats of w, nn of ii, nn of oi
    const float* wsrc = w + (size_t)node0 * VOCAB;
    for (int i = tid; i < nn * VOCAB / 4; i += 256)
        ((float4*)wl)[i] = ((const float4*)wsrc)[i];
    // (nn*VOCAB is always a multiple of 4)
    for (int i = tid; i < nn; i += 256) { sii[i] = ii[node0 + i]; soi[i] = oi[node0 + i]; }
    __syncthreads();

    int rbeg = g * 32;
    int rend = min(rbeg + 32, nn);
    for (int r = rbeg; r < rend; ++r) {
        const float4* wr = (const float4*)(wl + r * VOCAB);
        float acc = 0.f;
#pragma unroll
        for (int q = 0; q < VOCAB / 4; ++q) {
            float4 w4 = wr[q];
            acc += w4.x * ev[4 * q] + w4.y * ev[4 * q + 1]
                 + w4.z * ev[4 * q + 2] + w4.w * ev[4 * q + 3];
        }
        float val = fmaxf(acc * sii[r] + bj, 0.f);
        h1[(size_t)(node0 + r) * H + j] = __float2bfloat16(val * soi[r]);
    }
}

// ---------------- layer 2 ----------------

// gather over bf16 pre-scaled features, 4-wide padded batches for MLP
__global__ void k_gather_bf(const __hip_bfloat16* __restrict__ h,
                            const int* __restrict__ row_ptr, const int* __restrict__ col,
                            float* __restrict__ out, int n) {
    int gid = blockIdx.x * blockDim.x + threadIdx.x;
    int node = gid >> 6;
    int lane = gid & 63;
    if (node >= n) return;
    int beg = row_ptr[node];
    int end = row_ptr[node + 1];
    int lo = lane * 2;
    float a0 = 0.f, a1 = 0.f;
    for (int e = beg; e < end; e += 4) {
        int e1 = (e + 1 < end) ? e + 1 : e;
        int e2 = (e + 2 < end) ? e + 2 : e;
        int e3 = (e + 3 < end) ? e + 3 : e;
        int s0 = col[e], s1 = col[e1], s2 = col[e2], s3 = col[e3];
        __hip_bfloat162 v0 = *(const __hip_bfloat162*)(h + (size_t)s0 * H + lo);
        __hip_bfloat162 v1 = *(const __hip_bfloat162*)(h + (size_t)s1 * H + lo);
        __hip_bfloat162 v2 = *(const __hip_bfloat162*)(h + (size_t)s2 * H + lo);
        __hip_bfloat162 v3 = *(const __hip_bfloat162*)(h + (size_t)s3 * H + lo);
        float m1 = (e + 1 < end) ? 1.f : 0.f;
        float m2 = (e + 2 < end) ? 1.f : 0.f;
        float m3 = (e + 3 < end) ? 1.f : 0.f;
        float2 f0 = __bfloat1622float2(v0);
        float2 f1 = __bfloat1622float2(v1);
        float2 f2 = __bfloat1622float2(v2);
        float2 f3 = __bfloat1622float2(v3);
        a0 += f0.x + m1 * f1.x + m2 * f2.x + m3 * f3.x;
        a1 += f0.y + m1 * f1.y + m2 * f2.y + m3 * f3.y;
    }
    *(float2*)(out + (size_t)node * H + lane * 2) = make_float2(a0, a1);
}

// out[n][j] = relu( (in[n][:]*ii[n]) @ W + b[j] ); 16-row tile, 256 threads. In-place safe.
#define TROWS 16
__global__ void k_transform(const float* in, const float* __restrict__ ii,
                            const float* __restrict__ W, const float* __restrict__ b,
                            float* __restrict__ outp, int n) {
    __shared__ float At[TROWS][H];
    int block0 = blockIdx.x * TROWS;
    int tid = threadIdx.x;
    for (int i = tid; i < TROWS * H; i += 256) {
        int r = i >> 7, c = i & 127;
        int node = block0 + r;
        At[r][c] = (node < n) ? in[(size_t)node * H + c] * ii[node] : 0.f;
    }
    __syncthreads();
    int j = tid & 127;
    int ty = tid >> 7;  // 0..1, each handles 8 rows
    float acc[8];
#pragma unroll
    for (int r = 0; r < 8; ++r) acc[r] = 0.f;
    for (int k = 0; k < H; ++k) {
        float w = W[k * H + j];
#pragma unroll
        for (int r = 0; r < 8; ++r) acc[r] += At[ty * 8 + r][k] * w;
    }
    float bj = b[j];
#pragma unroll
    for (int r = 0; r < 8; ++r) {
        int node = block0 + ty * 8 + r;
        if (node < n) outp[(size_t)node * H + j] = fmaxf(acc[r] + bj, 0.f);
    }
}

// per-graph mean via binary search over sorted graph_ids; block per graph, 128 threads
__global__ void k_pool(const float* __restrict__ h, const int* __restrict__ gid,
                       float* __restrict__ hg, int n) {
    int g = blockIdx.x;
    __shared__ int sh[2];
    if (threadIdx.x == 0) {
        int lo = 0, hi = n;
        while (lo < hi) { int m = (lo + hi) >> 1; if (gid[m] < g) lo = m + 1; else hi = m; }
        sh[0] = lo;
        int lo2 = lo, hi2 = n;
        while (lo2 < hi2) { int m = (lo2 + hi2) >> 1; if (gid[m] < g + 1) lo2 = m + 1; else hi2 = m; }
        sh[1] = lo2;
    }
    __syncthreads();
    int beg = sh[0], end = sh[1];
    int c = threadIdx.x;
    float s = 0.f;
    for (int i = beg; i < end; ++i) s += h[(size_t)i * H + c];
    float cnt = (float)(end - beg);
    hg[g * H + c] = s / fmaxf(cnt, 1.f);
}

// ---------------- MLP head ----------------

__global__ void k_mlp1(const float* __restrict__ in, const float* __restrict__ W,
                       const float* __restrict__ b, float* __restrict__ out) {
    __shared__ float ld[128];
    int g = blockIdx.x;
    int t = threadIdx.x;
    ld[t] = in[g * H + t];
    __syncthreads();
    float acc = b[t];
    for (int k = 0; k < H; ++k) acc += ld[k] * W[k * H + t];
    out[g * H + t] = acc;
}

__global__ void k_bnstat(const float* __restrict__ x, float* __restrict__ stats, int G) {
    int c = blockIdx.x;
    float s = 0.f, s2 = 0.f;
    for (int g = threadIdx.x; g < G; g += blockDim.x) {
        float v = x[g * H + c];
        s += v; s2 += v * v;
    }
    __shared__ float rs[256], rs2[256];
    rs[threadIdx.x] = s; rs2[threadIdx.x] = s2;
    __syncthreads();
    for (int off = 128; off > 0; off >>= 1) {
        if (threadIdx.x < off) { rs[threadIdx.x] += rs[threadIdx.x + off]; rs2[threadIdx.x] += rs2[threadIdx.x + off]; }
        __syncthreads();
    }
    if (threadIdx.x == 0) {
        float mu = rs[0] / G;
        stats[c] = mu;
        stats[H + c] = rs2[0] / G - mu * mu;
    }
}

__global__ void k_mlp2bn(const float* __restrict__ t1, const float* __restrict__ stats,
                         const float* __restrict__ gam, const float* __restrict__ bet,
                         const float* __restrict__ W, const float* __restrict__ bias,
                         float* __restrict__ t2) {
    __shared__ float x[128];
    int g = blockIdx.x, t = threadIdx.x;
    float v = t1[g * H + t];
    v = (v - stats[t]) * rsqrtf(stats[H + t] + BN_EPS) * gam[t] + bet[t];
    x[t] = (v >= 0.f) ? v : 0.05f * v;
    __syncthreads();
    float acc = bias[t];
    for (int k = 0; k < H; ++k) acc += x[k] * W[k * H + t];
    t2[g * H + t] = acc;
}

__global__ void k_head(const float* __restrict__ t2, const float* __restrict__ stats,
                       const float* __restrict__ gam, const float* __restrict__ bet,
                       const float* __restrict__ e3w, const float* __restrict__ e3b,
                       const float* __restrict__ e4w, const float* __restrict__ e4b,
                       const float* __restrict__ e5w, const float* __restrict__ e5b,
                       float* __restrict__ out) {
    __shared__ float x[128], h3[64], h4[32];
    int g = blockIdx.x, t = threadIdx.x;
    float v = t2[g * H + t];
    v = (v - stats[t]) * rsqrtf(stats[H + t] + BN_EPS) * gam[t] + bet[t];
    x[t] = (v >= 0.f) ? v : 0.05f * v;
    __syncthreads();
    if (t < 64) {
        float a = e3b[t];
        for (int k = 0; k < 128; ++k) a += x[k] * e3w[k * 64 + t];
        h3[t] = (a >= 0.f) ? a : 0.1f * a;
    }
    __syncthreads();
    if (t < 32) {
        float a = e4b[t];
        for (int k = 0; k < 64; ++k) a += h3[k] * e4w[k * 32 + t];
        h4[t] = (a >= 0.f) ? a : 0.1f * a;
    }
    __syncthreads();
    if (t == 0) {
        float y0 = e5b[0], y1 = e5b[1];
        for (int k = 0; k < 32; ++k) {
            y0 += h4[k] * e5w[2 * k];
            y1 += h4[k] * e5w[2 * k + 1];
        }
        float m = fmaxf(y0, y1);
        float l = m + logf(expf(y0 - m) + expf(y1 - m));
        out[2 * g] = y0 - l;
        out[2 * g + 1] = y1 - l;
    }
}

extern "C" void kernel_launch(void* const* d_in, const int* in_sizes, int n_in,
                              void* d_out, int out_size, void* d_ws, size_t ws_size,
                              hipStream_t stream) {
    const int*   node_feat = (const int*)d_in[0];
    const int*   edge_src  = (const int*)d_in[1];
    const int*   edge_dst  = (const int*)d_in[2];
    const int*   graph_ids = (const int*)d_in[3];
    const float* emb  = (const float*)d_in[4];
    const float* W1   = (const float*)d_in[5];
    const float* b1   = (const float*)d_in[6];
    const float* W2   = (const float*)d_in[7];
    const float* b2   = (const float*)d_in[8];
    const float* e1_w = (const float*)d_in[9];
    const float* e1_b = (const float*)d_in[10];
    const float* e2_w = (const float*)d_in[11];
    const float* e2_b = (const float*)d_in[12];
    const float* e3_w = (const float*)d_in[13];
    const float* e3_b = (const float*)d_in[14];
    const float* e4_w = (const float*)d_in[15];
    const float* e4_b = (const float*)d_in[16];
    const float* e5_w = (const float*)d_in[17];
    const float* e5_b = (const float*)d_in[18];
    const float* bn0_g = (const float*)d_in[19];
    const float* bn0_b = (const float*)d_in[20];
    const float* bn1_g = (const float*)d_in[21];
    const float* bn1_b = (const float*)d_in[22];
    float* out = (float*)d_out;

    // workspace layout (floats)
    float* ws = (float*)d_ws;
    float* bufA = ws;                                   // N*H f32 (agg2 / h2, in-place)
    __hip_bfloat16* h1bf = (__hip_bfloat16*)(bufA + (size_t)N_NODES * H);  // N*H bf16
    float* after = (float*)(h1bf + (size_t)N_NODES * H);
    int*   cntO = (int*)after;                          // 50000
    int*   cntI = cntO + N_NODES;                       // 50000
    float* w    = (float*)(cntI + N_NODES);             // N*32 (contiguous w/ counters for one memset)
    float* oi   = w + (size_t)N_NODES * VOCAB;
    float* ii   = oi + N_NODES;
    int*   row_ptr = (int*)(ii + N_NODES);              // 50001 -> pad 50048
    int*   cursor  = row_ptr + 50048;                   // 50000 -> pad 50048
    int*   col  = cursor + 50048;                       // 600000
    float* hg   = (float*)(col + N_EDGES);              // 131072
    float* t1   = hg + N_GRAPHS * H;                    // 131072
    float* t2   = t1 + N_GRAPHS * H;                    // 131072
    float* stats = t2 + N_GRAPHS * H;                   // 512 (two stat sets)
    int*   bsum  = (int*)(stats + 4 * H);               // 256
    float* emb1  = (float*)(bsum + 256);                // 4096

    // one memset covers cntO, cntI, w (contiguous)
    hipMemsetAsync(cntO, 0, (2 * N_NODES + N_NODES * VOCAB) * sizeof(int), stream);

    const int eb = (N_EDGES + 255) / 256;
    k_count<<<eb, 256, 0, stream>>>(edge_src, edge_dst, cntO, cntI, N_EDGES);
    k_blocksum<<<SCAN_BLOCKS, 256, 0, stream>>>(cntI, bsum, N_NODES);
    k_scanbsum<<<1, 256, 0, stream>>>(bsum, row_ptr + N_NODES, SCAN_BLOCKS);
    k_scatterscan<<<SCAN_BLOCKS, 256, 0, stream>>>(cntI, cntO, bsum, row_ptr, cursor, oi, ii, N_NODES);
    k_fill<<<eb, 256, 0, stream>>>(edge_src, edge_dst, cursor, col, N_EDGES);

    // layer 1 (vocab space): hist -> emb1 -> h1 (bf16, pre-scaled by oi)
    k_emb1<<<VOCAB, 128, 0, stream>>>(emb, W1, emb1);
    k_hist<<<eb, 256, 0, stream>>>(edge_src, edge_dst, node_feat, oi, w, N_EDGES);
    k_h1<<<(N_NODES + H1_NODES - 1) / H1_NODES, 256, 0, stream>>>(w, emb1, ii, oi, b1, h1bf, N_NODES);

    // layer 2: batched gather of pre-scaled bf16 h1, transform in-place -> f32 h2
    const int gb = (N_NODES * 64 + 255) / 256;
    const int tb = (N_NODES + TROWS - 1) / TROWS;
    k_gather_bf<<<gb, 256, 0, stream>>>(h1bf, row_ptr, col, bufA, N_NODES);
    k_transform<<<tb, 256, 0, stream>>>(bufA, ii, W2, b2, bufA, N_NODES);

    // pooling
    k_pool<<<N_GRAPHS, 128, 0, stream>>>(bufA, graph_ids, hg, N_NODES);

    // MLP head (5 kernels)
    k_mlp1<<<N_GRAPHS, 128, 0, stream>>>(hg, e1_w, e1_b, t1);
    k_bnstat<<<H, 256, 0, stream>>>(t1, stats, N_GRAPHS);
    k_mlp2bn<<<N_GRAPHS, 128, 0, stream>>>(t1, stats, bn0_g, bn0_b, e2_w, e2_b, t2);
    k_bnstat<<<H, 256, 0, stream>>>(t2, stats + 2 * H, N_GRAPHS);
    k_head<<<N_GRAPHS, 128, 0, stream>>>(t2, stats + 2 * H, bn1_g, bn1_b,
                                         e3_w, e3_b, e4_w, e4_b, e5_w, e5_b, out);
}

// Round 7
// 245.563 us; speedup vs baseline: 1.8690x; 1.1057x over previous
//
#include <hip/hip_runtime.h>
#include <hip/hip_bf16.h>
#include <math.h>

#define N_NODES 50000
#define N_EDGES 600000
#define N_GRAPHS 1024
#define H 128
#define VOCAB 32
#define BN_EPS 1e-5f
#define SCAN_BLOCKS ((N_NODES + 255) / 256)   // 196
#define H1_NODES 64
#define MASK40 ((1ULL << 40) - 1)

// ---------------- edge passes ----------------

__global__ void k_countO(const int* __restrict__ src, int* __restrict__ cntO, int E) {
    int i = blockIdx.x * blockDim.x + threadIdx.x;
    if (i < E) atomicAdd(&cntO[src[i]], 1);
}

__global__ void k_oi(const int* __restrict__ cntO, float* __restrict__ oi, int n) {
    int i = blockIdx.x * blockDim.x + threadIdx.x;
    if (i < n) oi[i] = rsqrtf(fmaxf((float)cntO[i], 1.f));
}

// combined histogram+count: wc[dst][feat[src]] += (1<<40) | fixpt(oi[src])
// returned old count field = rank of this edge within its (dst,feat) bin
__global__ void k_hist64(const int* __restrict__ src, const int* __restrict__ dst,
                         const int* __restrict__ feat, const float* __restrict__ oi,
                         unsigned long long* __restrict__ wc,
                         unsigned char* __restrict__ rank8, int E) {
    int i = blockIdx.x * blockDim.x + threadIdx.x;
    if (i >= E) return;
    int s = src[i], d = dst[i], v = feat[s];
    unsigned long long q = (unsigned long long)__float2uint_rn(oi[s] * 16777216.0f);
    unsigned long long old = atomicAdd(&wc[(size_t)d * VOCAB + v], (1ULL << 40) | q);
    rank8[i] = (unsigned char)(old >> 40);
}

// wave per node: cntI = sum of bin counts, binbase = exclusive scan of bin counts
__global__ void k_nodebins(const unsigned long long* __restrict__ wc,
                           int* __restrict__ cntI, unsigned char* __restrict__ binbase,
                           int n) {
    int wid = threadIdx.x >> 6;
    int lane = threadIdx.x & 63;
    int node = blockIdx.x * 4 + wid;
    if (node >= n || lane >= VOCAB) return;
    int c = (int)(wc[(size_t)node * VOCAB + lane] >> 40);
    int inc = c;
#pragma unroll
    for (int off = 1; off < VOCAB; off <<= 1) {
        int u = __shfl_up(inc, off, 64);
        if (lane >= off) inc += u;
    }
    binbase[(size_t)node * VOCAB + lane] = (unsigned char)(inc - c);
    if (lane == VOCAB - 1) cntI[node] = inc;
}

// atomic-free CSR fill
__global__ void k_fill2(const int* __restrict__ src, const int* __restrict__ dst,
                        const int* __restrict__ feat, const int* __restrict__ row_ptr,
                        const unsigned char* __restrict__ binbase,
                        const unsigned char* __restrict__ rank8,
                        int* __restrict__ col, int E) {
    int i = blockIdx.x * blockDim.x + threadIdx.x;
    if (i >= E) return;
    int s = src[i], d = dst[i], v = feat[s];
    int slot = row_ptr[d] + (int)binbase[(size_t)d * VOCAB + v] + (int)rank8[i];
    col[slot] = s;
}

// ---------------- scan ----------------

__global__ void k_blocksum(const int* __restrict__ cnt, int* __restrict__ bsum, int n) {
    __shared__ int red[256];
    int i = blockIdx.x * 256 + threadIdx.x;
    red[threadIdx.x] = (i < n) ? cnt[i] : 0;
    __syncthreads();
    for (int off = 128; off > 0; off >>= 1) {
        if (threadIdx.x < off) red[threadIdx.x] += red[threadIdx.x + off];
        __syncthreads();
    }
    if (threadIdx.x == 0) bsum[blockIdx.x] = red[0];
}

__global__ void k_scanbsum(int* __restrict__ bsum, int* __restrict__ row_ptr_last, int nb) {
    __shared__ int sh[256];
    int t = threadIdx.x;
    int v = (t < nb) ? bsum[t] : 0;
    sh[t] = v;
    __syncthreads();
    for (int off = 1; off < 256; off <<= 1) {
        int u = (t >= off) ? sh[t - off] : 0;
        __syncthreads();
        sh[t] += u;
        __syncthreads();
    }
    if (t < nb) bsum[t] = sh[t] - v;
    if (t == nb - 1) *row_ptr_last = sh[t];
}

__global__ void k_scatterscan(const int* __restrict__ cntI, const int* __restrict__ bsum,
                              int* __restrict__ row_ptr, float* __restrict__ ii, int n) {
    __shared__ int sh[256];
    int i = blockIdx.x * 256 + threadIdx.x;
    int t = threadIdx.x;
    int v = (i < n) ? cntI[i] : 0;
    sh[t] = v;
    __syncthreads();
    for (int off = 1; off < 256; off <<= 1) {
        int u = (t >= off) ? sh[t - off] : 0;
        __syncthreads();
        sh[t] += u;
        __syncthreads();
    }
    if (i < n) {
        row_ptr[i] = bsum[blockIdx.x] + sh[t] - v;
        ii[i] = rsqrtf(fmaxf((float)v, 1.f));
    }
}

// ---------------- layer 1 ----------------

// emb1 = emb @ W1  (32 x 128)
__global__ void k_emb1(const float* __restrict__ emb, const float* __restrict__ W1,
                       float* __restrict__ emb1) {
    int v = blockIdx.x;
    int j = threadIdx.x;
    float acc = 0.f;
    for (int k = 0; k < H; ++k) acc += emb[v * H + k] * W1[k * H + j];
    emb1[v * H + j] = acc;
}

// h1[node][j] = relu( ii*(w_row @ emb1[:,j]) + b1[j] ) * oi, bf16.
// wc rows decoded at stage time into LDS floats; emb1 column in VGPRs.
__global__ void k_h1(const unsigned long long* __restrict__ wc, const float* __restrict__ emb1,
                     const float* __restrict__ ii, const float* __restrict__ oi,
                     const float* __restrict__ b1, __hip_bfloat16* __restrict__ h1, int n) {
    __shared__ float wl[H1_NODES * VOCAB];   // 8 KB
    __shared__ float sii[H1_NODES], soi[H1_NODES];
    int tid = threadIdx.x;
    int j = tid & 127;
    int g = tid >> 7;
    float ev[VOCAB];
#pragma unroll
    for (int v = 0; v < VOCAB; ++v) ev[v] = emb1[v * H + j];
    float bj = b1[j];

    int node0 = blockIdx.x * H1_NODES;
    int nn = min(H1_NODES, n - node0);
    const unsigned long long* wsrc = wc + (size_t)node0 * VOCAB;
    for (int i = tid; i < nn * VOCAB; i += 256) {
        unsigned long long p = wsrc[i];
        float lo = (float)((unsigned)p & 0xFFFFFFu);
        float hi = (float)((unsigned)(p >> 24) & 0xFFFFu);
        wl[i] = fmaf(lo, 1.0f / 16777216.0f, hi);
    }
    for (int i = tid; i < nn; i += 256) { sii[i] = ii[node0 + i]; soi[i] = oi[node0 + i]; }
    __syncthreads();

    int rbeg = g * 32;
    int rend = min(rbeg + 32, nn);
    for (int r = rbeg; r < rend; ++r) {
        const float4* wr = (const float4*)(wl + r * VOCAB);
        float acc = 0.f;
#pragma unroll
        for (int q = 0; q < VOCAB / 4; ++q) {
            float4 w4 = wr[q];
            acc += w4.x * ev[4 * q] + w4.y * ev[4 * q + 1]
                 + w4.z * ev[4 * q + 2] + w4.w * ev[4 * q + 3];
        }
        float val = fmaxf(acc * sii[r] + bj, 0.f);
        h1[(size_t)(node0 + r) * H + j] = __float2bfloat16(val * soi[r]);
    }
}

// ---------------- layer 2 ----------------

// gather of bf16 pre-scaled features; 8-wide unmasked batches + scalar tail
__global__ void k_gather_bf(const __hip_bfloat16* __restrict__ h,
                            const int* __restrict__ row_ptr, const int* __restrict__ col,
                            float* __restrict__ out, int n) {
    int gid = blockIdx.x * blockDim.x + threadIdx.x;
    int node = gid >> 6;
    int lane = gid & 63;
    if (node >= n) return;
    int beg = row_ptr[node];
    int end = row_ptr[node + 1];
    int lo = lane * 2;
    float a0 = 0.f, a1 = 0.f;
    int e = beg;
    for (; e + 8 <= end; e += 8) {
#pragma unroll
        for (int k = 0; k < 8; ++k) {
            int s = col[e + k];
            float2 f = __bfloat1622float2(*(const __hip_bfloat162*)(h + (size_t)s * H + lo));
            a0 += f.x; a1 += f.y;
        }
    }
    for (; e < end; ++e) {
        int s = col[e];
        float2 f = __bfloat1622float2(*(const __hip_bfloat162*)(h + (size_t)s * H + lo));
        a0 += f.x; a1 += f.y;
    }
    *(float2*)(out + (size_t)node * H + lane * 2) = make_float2(a0, a1);
}

// out[n][j] = relu( (in[n][:]*ii[n]) @ W + b[j] ); 16-row tile, in-place safe
#define TROWS 16
__global__ void k_transform(const float* in, const float* __restrict__ ii,
                            const float* __restrict__ W, const float* __restrict__ b,
                            float* __restrict__ outp, int n) {
    __shared__ float At[TROWS][H];
    int block0 = blockIdx.x * TROWS;
    int tid = threadIdx.x;
    for (int i = tid; i < TROWS * H; i += 256) {
        int r = i >> 7, c = i & 127;
        int node = block0 + r;
        At[r][c] = (node < n) ? in[(size_t)node * H + c] * ii[node] : 0.f;
    }
    __syncthreads();
    int j = tid & 127;
    int ty = tid >> 7;
    float acc[8];
#pragma unroll
    for (int r = 0; r < 8; ++r) acc[r] = 0.f;
    for (int k = 0; k < H; ++k) {
        float w = W[k * H + j];
#pragma unroll
        for (int r = 0; r < 8; ++r) acc[r] += At[ty * 8 + r][k] * w;
    }
    float bj = b[j];
#pragma unroll
    for (int r = 0; r < 8; ++r) {
        int node = block0 + ty * 8 + r;
        if (node < n) outp[(size_t)node * H + j] = fmaxf(acc[r] + bj, 0.f);
    }
}

// per-graph mean via binary search over sorted graph_ids
__global__ void k_pool(const float* __restrict__ h, const int* __restrict__ gid,
                       float* __restrict__ hg, int n) {
    int g = blockIdx.x;
    __shared__ int sh[2];
    if (threadIdx.x == 0) {
        int lo = 0, hi = n;
        while (lo < hi) { int m = (lo + hi) >> 1; if (gid[m] < g) lo = m + 1; else hi = m; }
        sh[0] = lo;
        int lo2 = lo, hi2 = n;
        while (lo2 < hi2) { int m = (lo2 + hi2) >> 1; if (gid[m] < g + 1) lo2 = m + 1; else hi2 = m; }
        sh[1] = lo2;
    }
    __syncthreads();
    int beg = sh[0], end = sh[1];
    int c = threadIdx.x;
    float s = 0.f;
    for (int i = beg; i < end; ++i) s += h[(size_t)i * H + c];
    float cnt = (float)(end - beg);
    hg[g * H + c] = s / fmaxf(cnt, 1.f);
}

// ---------------- MLP head ----------------

__global__ void k_mlp1(const float* __restrict__ in, const float* __restrict__ W,
                       const float* __restrict__ b, float* __restrict__ out) {
    __shared__ float ld[128];
    int g = blockIdx.x;
    int t = threadIdx.x;
    ld[t] = in[g * H + t];
    __syncthreads();
    float acc = b[t];
    for (int k = 0; k < H; ++k) acc += ld[k] * W[k * H + t];
    out[g * H + t] = acc;
}

__global__ void k_bnstat(const float* __restrict__ x, float* __restrict__ stats, int G) {
    int c = blockIdx.x;
    float s = 0.f, s2 = 0.f;
    for (int g = threadIdx.x; g < G; g += blockDim.x) {
        float v = x[g * H + c];
        s += v; s2 += v * v;
    }
    __shared__ float rs[256], rs2[256];
    rs[threadIdx.x] = s; rs2[threadIdx.x] = s2;
    __syncthreads();
    for (int off = 128; off > 0; off >>= 1) {
        if (threadIdx.x < off) { rs[threadIdx.x] += rs[threadIdx.x + off]; rs2[threadIdx.x] += rs2[threadIdx.x + off]; }
        __syncthreads();
    }
    if (threadIdx.x == 0) {
        float mu = rs[0] / G;
        stats[c] = mu;
        stats[H + c] = rs2[0] / G - mu * mu;
    }
}

__global__ void k_mlp2bn(const float* __restrict__ t1, const float* __restrict__ stats,
                         const float* __restrict__ gam, const float* __restrict__ bet,
                         const float* __restrict__ W, const float* __restrict__ bias,
                         float* __restrict__ t2) {
    __shared__ float x[128];
    int g = blockIdx.x, t = threadIdx.x;
    float v = t1[g * H + t];
    v = (v - stats[t]) * rsqrtf(stats[H + t] + BN_EPS) * gam[t] + bet[t];
    x[t] = (v >= 0.f) ? v : 0.05f * v;
    __syncthreads();
    float acc = bias[t];
    for (int k = 0; k < H; ++k) acc += x[k] * W[k * H + t];
    t2[g * H + t] = acc;
}

__global__ void k_head(const float* __restrict__ t2, const float* __restrict__ stats,
                       const float* __restrict__ gam, const float* __restrict__ bet,
                       const float* __restrict__ e3w, const float* __restrict__ e3b,
                       const float* __restrict__ e4w, const float* __restrict__ e4b,
                       const float* __restrict__ e5w, const float* __restrict__ e5b,
                       float* __restrict__ out) {
    __shared__ float x[128], h3[64], h4[32];
    int g = blockIdx.x, t = threadIdx.x;
    float v = t2[g * H + t];
    v = (v - stats[t]) * rsqrtf(stats[H + t] + BN_EPS) * gam[t] + bet[t];
    x[t] = (v >= 0.f) ? v : 0.05f * v;
    __syncthreads();
    if (t < 64) {
        float a = e3b[t];
        for (int k = 0; k < 128; ++k) a += x[k] * e3w[k * 64 + t];
        h3[t] = (a >= 0.f) ? a : 0.1f * a;
    }
    __syncthreads();
    if (t < 32) {
        float a = e4b[t];
        for (int k = 0; k < 64; ++k) a += h3[k] * e4w[k * 32 + t];
        h4[t] = (a >= 0.f) ? a : 0.1f * a;
    }
    __syncthreads();
    if (t == 0) {
        float y0 = e5b[0], y1 = e5b[1];
        for (int k = 0; k < 32; ++k) {
            y0 += h4[k] * e5w[2 * k];
            y1 += h4[k] * e5w[2 * k + 1];
        }
        float m = fmaxf(y0, y1);
        float l = m + logf(expf(y0 - m) + expf(y1 - m));
        out[2 * g] = y0 - l;
        out[2 * g + 1] = y1 - l;
    }
}

extern "C" void kernel_launch(void* const* d_in, const int* in_sizes, int n_in,
                              void* d_out, int out_size, void* d_ws, size_t ws_size,
                              hipStream_t stream) {
    const int*   node_feat = (const int*)d_in[0];
    const int*   edge_src  = (const int*)d_in[1];
    const int*   edge_dst  = (const int*)d_in[2];
    const int*   graph_ids = (const int*)d_in[3];
    const float* emb  = (const float*)d_in[4];
    const float* W1   = (const float*)d_in[5];
    const float* b1   = (const float*)d_in[6];
    const float* W2   = (const float*)d_in[7];
    const float* b2   = (const float*)d_in[8];
    const float* e1_w = (const float*)d_in[9];
    const float* e1_b = (const float*)d_in[10];
    const float* e2_w = (const float*)d_in[11];
    const float* e2_b = (const float*)d_in[12];
    const float* e3_w = (const float*)d_in[13];
    const float* e3_b = (const float*)d_in[14];
    const float* e4_w = (const float*)d_in[15];
    const float* e4_b = (const float*)d_in[16];
    const float* e5_w = (const float*)d_in[17];
    const float* e5_b = (const float*)d_in[18];
    const float* bn0_g = (const float*)d_in[19];
    const float* bn0_b = (const float*)d_in[20];
    const float* bn1_g = (const float*)d_in[21];
    const float* bn1_b = (const float*)d_in[22];
    float* out = (float*)d_out;

    // workspace layout
    float* ws = (float*)d_ws;
    float* bufA = ws;                                                     // N*H f32
    __hip_bfloat16* h1bf = (__hip_bfloat16*)(bufA + (size_t)N_NODES * H); // N*H bf16
    int*   cntO = (int*)(h1bf + (size_t)N_NODES * H);                     // 50000 (8B-aligned: 200000%8==0)
    unsigned long long* wc = (unsigned long long*)(cntO + N_NODES);       // N*32 u64 = 12.8MB
    float* oi   = (float*)(wc + (size_t)N_NODES * VOCAB);
    float* ii   = oi + N_NODES;
    int*   cntI = (int*)(ii + N_NODES);
    int*   row_ptr = cntI + N_NODES;                                      // 50001 -> pad 50048
    int*   col  = row_ptr + 50048;                                        // 600000
    unsigned char* binbase = (unsigned char*)(col + N_EDGES);             // N*32 = 1.6MB
    unsigned char* rank8   = binbase + (size_t)N_NODES * VOCAB;           // 600000
    float* hg   = (float*)(rank8 + ((N_EDGES + 63) & ~63));               // aligned
    float* t1   = hg + N_GRAPHS * H;
    float* t2   = t1 + N_GRAPHS * H;
    float* stats = t2 + N_GRAPHS * H;                                     // 512
    int*   bsum  = (int*)(stats + 4 * H);                                 // 256
    float* emb1  = (float*)(bsum + 256);                                  // 4096

    // one memset covers cntO + wc (contiguous)
    hipMemsetAsync(cntO, 0, N_NODES * sizeof(int) + (size_t)N_NODES * VOCAB * 8, stream);

    const int eb = (N_EDGES + 255) / 256;
    k_countO<<<eb, 256, 0, stream>>>(edge_src, cntO, N_EDGES);
    k_oi<<<SCAN_BLOCKS, 256, 0, stream>>>(cntO, oi, N_NODES);
    k_emb1<<<VOCAB, 128, 0, stream>>>(emb, W1, emb1);
    k_hist64<<<eb, 256, 0, stream>>>(edge_src, edge_dst, node_feat, oi, wc, rank8, N_EDGES);
    k_nodebins<<<(N_NODES + 3) / 4, 256, 0, stream>>>(wc, cntI, binbase, N_NODES);
    k_blocksum<<<SCAN_BLOCKS, 256, 0, stream>>>(cntI, bsum, N_NODES);
    k_scanbsum<<<1, 256, 0, stream>>>(bsum, row_ptr + N_NODES, SCAN_BLOCKS);
    k_scatterscan<<<SCAN_BLOCKS, 256, 0, stream>>>(cntI, bsum, row_ptr, ii, N_NODES);
    k_fill2<<<eb, 256, 0, stream>>>(edge_src, edge_dst, node_feat, row_ptr, binbase, rank8, col, N_EDGES);

    // layer 1: h1 = relu(ii*(w@emb1)+b1)*oi -> bf16
    k_h1<<<(N_NODES + H1_NODES - 1) / H1_NODES, 256, 0, stream>>>(wc, emb1, ii, oi, b1, h1bf, N_NODES);

    // layer 2
    const int gb = (N_NODES * 64 + 255) / 256;
    const int tb = (N_NODES + TROWS - 1) / TROWS;
    k_gather_bf<<<gb, 256, 0, stream>>>(h1bf, row_ptr, col, bufA, N_NODES);
    k_transform<<<tb, 256, 0, stream>>>(bufA, ii, W2, b2, bufA, N_NODES);

    // pooling
    k_pool<<<N_GRAPHS, 128, 0, stream>>>(bufA, graph_ids, hg, N_NODES);

    // MLP head
    k_mlp1<<<N_GRAPHS, 128, 0, stream>>>(hg, e1_w, e1_b, t1);
    k_bnstat<<<H, 256, 0, stream>>>(t1, stats, N_GRAPHS);
    k_mlp2bn<<<N_GRAPHS, 128, 0, stream>>>(t1, stats, bn0_g, bn0_b, e2_w, e2_b, t2);
    k_bnstat<<<H, 256, 0, stream>>>(t2, stats + 2 * H, N_GRAPHS);
    k_head<<<N_GRAPHS, 128, 0, stream>>>(t2, stats + 2 * H, bn1_g, bn1_b,
                                         e3_w, e3_b, e4_w, e4_b, e5_w, e5_b, out);
}

// Round 8
// 230.309 us; speedup vs baseline: 1.9928x; 1.0662x over previous
//
#include <hip/hip_runtime.h>
#include <hip/hip_bf16.h>
#include <math.h>

#define N_NODES 50000
#define N_PAD   50048
#define N_EDGES 600000
#define N_GRAPHS 1024
#define H 128
#define VOCAB 32
#define BN_EPS 1e-5f
#define SCAN_BLOCKS ((N_NODES + 255) / 256)   // 196
#define H1_NODES 64

typedef short bf8_t __attribute__((ext_vector_type(8)));
typedef float f4_t __attribute__((ext_vector_type(4)));

// ---------------- edge passes ----------------

__global__ void k_countO(const int* __restrict__ src, int* __restrict__ cntO, int E) {
    int i = blockIdx.x * blockDim.x + threadIdx.x;
    if (i < E) atomicAdd(&cntO[src[i]], 1);
}

__global__ void k_oi(const int* __restrict__ cntO, float* __restrict__ oi, int n) {
    int i = blockIdx.x * blockDim.x + threadIdx.x;
    if (i < n) oi[i] = rsqrtf(fmaxf((float)cntO[i], 1.f));
}

// combined histogram+count: wc[dst][feat[src]] += (1<<40) | fixpt(oi[src])
__global__ void k_hist64(const int* __restrict__ src, const int* __restrict__ dst,
                         const int* __restrict__ feat, const float* __restrict__ oi,
                         unsigned long long* __restrict__ wc,
                         unsigned char* __restrict__ rank8, int E) {
    int i = blockIdx.x * blockDim.x + threadIdx.x;
    if (i >= E) return;
    int s = src[i], d = dst[i], v = feat[s];
    unsigned long long q = (unsigned long long)__float2uint_rn(oi[s] * 16777216.0f);
    unsigned long long old = atomicAdd(&wc[(size_t)d * VOCAB + v], (1ULL << 40) | q);
    rank8[i] = (unsigned char)(old >> 40);
}

// wave per node: cntI = sum of bin counts, binbase = exclusive scan of bin counts
__global__ void k_nodebins(const unsigned long long* __restrict__ wc,
                           int* __restrict__ cntI, unsigned char* __restrict__ binbase,
                           int n) {
    int wid = threadIdx.x >> 6;
    int lane = threadIdx.x & 63;
    int node = blockIdx.x * 4 + wid;
    if (node >= n || lane >= VOCAB) return;
    int c = (int)(wc[(size_t)node * VOCAB + lane] >> 40);
    int inc = c;
#pragma unroll
    for (int off = 1; off < VOCAB; off <<= 1) {
        int u = __shfl_up(inc, off, 64);
        if (lane >= off) inc += u;
    }
    binbase[(size_t)node * VOCAB + lane] = (unsigned char)(inc - c);
    if (lane == VOCAB - 1) cntI[node] = inc;
}

// atomic-free CSR fill
__global__ void k_fill2(const int* __restrict__ src, const int* __restrict__ dst,
                        const int* __restrict__ feat, const int* __restrict__ row_ptr,
                        const unsigned char* __restrict__ binbase,
                        const unsigned char* __restrict__ rank8,
                        int* __restrict__ col, int E) {
    int i = blockIdx.x * blockDim.x + threadIdx.x;
    if (i >= E) return;
    int s = src[i], d = dst[i], v = feat[s];
    int slot = row_ptr[d] + (int)binbase[(size_t)d * VOCAB + v] + (int)rank8[i];
    col[slot] = s;
}

// ---------------- scan ----------------

__global__ void k_blocksum(const int* __restrict__ cnt, int* __restrict__ bsum, int n) {
    __shared__ int red[256];
    int i = blockIdx.x * 256 + threadIdx.x;
    red[threadIdx.x] = (i < n) ? cnt[i] : 0;
    __syncthreads();
    for (int off = 128; off > 0; off >>= 1) {
        if (threadIdx.x < off) red[threadIdx.x] += red[threadIdx.x + off];
        __syncthreads();
    }
    if (threadIdx.x == 0) bsum[blockIdx.x] = red[0];
}

__global__ void k_scanbsum(int* __restrict__ bsum, int* __restrict__ row_ptr_last, int nb) {
    __shared__ int sh[256];
    int t = threadIdx.x;
    int v = (t < nb) ? bsum[t] : 0;
    sh[t] = v;
    __syncthreads();
    for (int off = 1; off < 256; off <<= 1) {
        int u = (t >= off) ? sh[t - off] : 0;
        __syncthreads();
        sh[t] += u;
        __syncthreads();
    }
    if (t < nb) bsum[t] = sh[t] - v;
    if (t == nb - 1) *row_ptr_last = sh[t];
}

__global__ void k_scatterscan(const int* __restrict__ cntI, const int* __restrict__ bsum,
                              int* __restrict__ row_ptr, float* __restrict__ ii, int n) {
    __shared__ int sh[256];
    int i = blockIdx.x * 256 + threadIdx.x;
    int t = threadIdx.x;
    int v = (i < n) ? cntI[i] : 0;
    sh[t] = v;
    __syncthreads();
    for (int off = 1; off < 256; off <<= 1) {
        int u = (t >= off) ? sh[t - off] : 0;
        __syncthreads();
        sh[t] += u;
        __syncthreads();
    }
    if (i < n) {
        row_ptr[i] = bsum[blockIdx.x] + sh[t] - v;
        ii[i] = rsqrtf(fmaxf((float)v, 1.f));
    }
}

// ---------------- layer 1 ----------------

// emb1 = emb @ W1  (32 x 128)
__global__ void k_emb1(const float* __restrict__ emb, const float* __restrict__ W1,
                       float* __restrict__ emb1) {
    int v = blockIdx.x;
    int j = threadIdx.x;
    float acc = 0.f;
    for (int k = 0; k < H; ++k) acc += emb[v * H + k] * W1[k * H + j];
    emb1[v * H + j] = acc;
}

// WT[c][k] = bf16(W2[k][c])
__global__ void k_w2t(const float* __restrict__ W, __hip_bfloat16* __restrict__ WT) {
    int k = blockIdx.x;
    int c = threadIdx.x;
    WT[(size_t)c * H + k] = __float2bfloat16(W[(size_t)k * H + c]);
}

// h1[node][j] = relu( ii*(w_row @ emb1[:,j]) + b1[j] ) * oi, bf16.
__global__ void k_h1(const unsigned long long* __restrict__ wc, const float* __restrict__ emb1,
                     const float* __restrict__ ii, const float* __restrict__ oi,
                     const float* __restrict__ b1, __hip_bfloat16* __restrict__ h1, int n) {
    __shared__ float wl[H1_NODES * VOCAB];   // 8 KB
    __shared__ float sii[H1_NODES], soi[H1_NODES];
    int tid = threadIdx.x;
    int j = tid & 127;
    int g = tid >> 7;
    float ev[VOCAB];
#pragma unroll
    for (int v = 0; v < VOCAB; ++v) ev[v] = emb1[v * H + j];
    float bj = b1[j];

    int node0 = blockIdx.x * H1_NODES;
    int nn = min(H1_NODES, n - node0);
    const unsigned long long* wsrc = wc + (size_t)node0 * VOCAB;
    for (int i = tid; i < nn * VOCAB; i += 256) {
        unsigned long long p = wsrc[i];
        float lo = (float)((unsigned)p & 0xFFFFFFu);
        float hi = (float)((unsigned)(p >> 24) & 0xFFFFu);
        wl[i] = fmaf(lo, 1.0f / 16777216.0f, hi);
    }
    for (int i = tid; i < nn; i += 256) { sii[i] = ii[node0 + i]; soi[i] = oi[node0 + i]; }
    __syncthreads();

    int rbeg = g * 32;
    int rend = min(rbeg + 32, nn);
    for (int r = rbeg; r < rend; ++r) {
        const float4* wr = (const float4*)(wl + r * VOCAB);
        float acc = 0.f;
#pragma unroll
        for (int q = 0; q < VOCAB / 4; ++q) {
            float4 w4 = wr[q];
            acc += w4.x * ev[4 * q] + w4.y * ev[4 * q + 1]
                 + w4.z * ev[4 * q + 2] + w4.w * ev[4 * q + 3];
        }
        float val = fmaxf(acc * sii[r] + bj, 0.f);
        h1[(size_t)(node0 + r) * H + j] = __float2bfloat16(val * soi[r]);
    }
}

// ---------------- layer 2 ----------------

// gather of bf16 pre-scaled features; 8-wide unmasked batches + scalar tail; bf16 out
__global__ void k_gather_bf(const __hip_bfloat16* __restrict__ h,
                            const int* __restrict__ row_ptr, const int* __restrict__ col,
                            __hip_bfloat16* __restrict__ out, int n) {
    int gid = blockIdx.x * blockDim.x + threadIdx.x;
    int node = gid >> 6;
    int lane = gid & 63;
    if (node >= n) return;
    int beg = row_ptr[node];
    int end = row_ptr[node + 1];
    int lo = lane * 2;
    float a0 = 0.f, a1 = 0.f;
    int e = beg;
    for (; e + 8 <= end; e += 8) {
#pragma unroll
        for (int k = 0; k < 8; ++k) {
            int s = col[e + k];
            float2 f = __bfloat1622float2(*(const __hip_bfloat162*)(h + (size_t)s * H + lo));
            a0 += f.x; a1 += f.y;
        }
    }
    for (; e < end; ++e) {
        int s = col[e];
        float2 f = __bfloat1622float2(*(const __hip_bfloat162*)(h + (size_t)s * H + lo));
        a0 += f.x; a1 += f.y;
    }
    *(__hip_bfloat162*)(out + (size_t)node * H + lo) =
        __float22bfloat162_rn(make_float2(a0, a1));
}

// MFMA transform: out[m][c] = relu( ii[m] * (A @ W)[m][c] + b[c] )
// A: [N_PAD][128] bf16 (agg), WT: [c][k] bf16. 4 waves/block, 64 rows/block.
__global__ void k_transform_mfma(const __hip_bfloat16* __restrict__ A,
                                 const __hip_bfloat16* __restrict__ WT,
                                 const float* __restrict__ ii,
                                 const float* __restrict__ b,
                                 float* __restrict__ outp, int n) {
    int wave = threadIdx.x >> 6;
    int lane = threadIdx.x & 63;
    int row0 = blockIdx.x * 64 + wave * 16;
    int rl = lane & 15;       // A-row / B-col within tile
    int kg = lane >> 4;       // k-group
    f4_t acc[8];
#pragma unroll
    for (int t = 0; t < 8; ++t) acc[t] = f4_t{0.f, 0.f, 0.f, 0.f};
    const __hip_bfloat16* arow = A + (size_t)(row0 + rl) * H + kg * 8;
#pragma unroll
    for (int ks = 0; ks < 4; ++ks) {
        bf8_t a = *(const bf8_t*)(arow + ks * 32);
#pragma unroll
        for (int t = 0; t < 8; ++t) {
            bf8_t bf = *(const bf8_t*)(WT + (size_t)(t * 16 + rl) * H + ks * 32 + kg * 8);
            acc[t] = __builtin_amdgcn_mfma_f32_16x16x32_bf16(a, bf, acc[t], 0, 0, 0);
        }
    }
    // D: col = lane&15 within tile, row = kg*4 + reg
    int rbase = row0 + kg * 4;
#pragma unroll
    for (int r = 0; r < 4; ++r) {
        int node = rbase + r;
        if (node < n) {
            float s = ii[node];
#pragma unroll
            for (int t = 0; t < 8; ++t) {
                int c = t * 16 + rl;
                float v = acc[t][r] * s + b[c];
                outp[(size_t)node * H + c] = fmaxf(v, 0.f);
            }
        }
    }
}

// per-graph mean via binary search over sorted graph_ids
__global__ void k_pool(const float* __restrict__ h, const int* __restrict__ gid,
                       float* __restrict__ hg, int n) {
    int g = blockIdx.x;
    __shared__ int sh[2];
    if (threadIdx.x == 0) {
        int lo = 0, hi = n;
        while (lo < hi) { int m = (lo + hi) >> 1; if (gid[m] < g) lo = m + 1; else hi = m; }
        sh[0] = lo;
        int lo2 = lo, hi2 = n;
        while (lo2 < hi2) { int m = (lo2 + hi2) >> 1; if (gid[m] < g + 1) lo2 = m + 1; else hi2 = m; }
        sh[1] = lo2;
    }
    __syncthreads();
    int beg = sh[0], end = sh[1];
    int c = threadIdx.x;
    float s = 0.f;
    for (int i = beg; i < end; ++i) s += h[(size_t)i * H + c];
    float cnt = (float)(end - beg);
    hg[g * H + c] = s / fmaxf(cnt, 1.f);
}

// ---------------- MLP head ----------------

__global__ void k_mlp1(const float* __restrict__ in, const float* __restrict__ W,
                       const float* __restrict__ b, float* __restrict__ out) {
    __shared__ float ld[128];
    int g = blockIdx.x;
    int t = threadIdx.x;
    ld[t] = in[g * H + t];
    __syncthreads();
    float acc = b[t];
    for (int k = 0; k < H; ++k) acc += ld[k] * W[k * H + t];
    out[g * H + t] = acc;
}

__global__ void k_bnstat(const float* __restrict__ x, float* __restrict__ stats, int G) {
    int c = blockIdx.x;
    float s = 0.f, s2 = 0.f;
    for (int g = threadIdx.x; g < G; g += blockDim.x) {
        float v = x[g * H + c];
        s += v; s2 += v * v;
    }
    __shared__ float rs[256], rs2[256];
    rs[threadIdx.x] = s; rs2[threadIdx.x] = s2;
    __syncthreads();
    for (int off = 128; off > 0; off >>= 1) {
        if (threadIdx.x < off) { rs[threadIdx.x] += rs[threadIdx.x + off]; rs2[threadIdx.x] += rs2[threadIdx.x + off]; }
        __syncthreads();
    }
    if (threadIdx.x == 0) {
        float mu = rs[0] / G;
        stats[c] = mu;
        stats[H + c] = rs2[0] / G - mu * mu;
    }
}

__global__ void k_mlp2bn(const float* __restrict__ t1, const float* __restrict__ stats,
                         const float* __restrict__ gam, const float* __restrict__ bet,
                         const float* __restrict__ W, const float* __restrict__ bias,
                         float* __restrict__ t2) {
    __shared__ float x[128];
    int g = blockIdx.x, t = threadIdx.x;
    float v = t1[g * H + t];
    v = (v - stats[t]) * rsqrtf(stats[H + t] + BN_EPS) * gam[t] + bet[t];
    x[t] = (v >= 0.f) ? v : 0.05f * v;
    __syncthreads();
    float acc = bias[t];
    for (int k = 0; k < H; ++k) acc += x[k] * W[k * H + t];
    t2[g * H + t] = acc;
}

__global__ void k_head(const float* __restrict__ t2, const float* __restrict__ stats,
                       const float* __restrict__ gam, const float* __restrict__ bet,
                       const float* __restrict__ e3w, const float* __restrict__ e3b,
                       const float* __restrict__ e4w, const float* __restrict__ e4b,
                       const float* __restrict__ e5w, const float* __restrict__ e5b,
                       float* __restrict__ out) {
    __shared__ float x[128], h3[64], h4[32];
    int g = blockIdx.x, t = threadIdx.x;
    float v = t2[g * H + t];
    v = (v - stats[t]) * rsqrtf(stats[H + t] + BN_EPS) * gam[t] + bet[t];
    x[t] = (v >= 0.f) ? v : 0.05f * v;
    __syncthreads();
    if (t < 64) {
        float a = e3b[t];
        for (int k = 0; k < 128; ++k) a += x[k] * e3w[k * 64 + t];
        h3[t] = (a >= 0.f) ? a : 0.1f * a;
    }
    __syncthreads();
    if (t < 32) {
        float a = e4b[t];
        for (int k = 0; k < 64; ++k) a += h3[k] * e4w[k * 32 + t];
        h4[t] = (a >= 0.f) ? a : 0.1f * a;
    }
    __syncthreads();
    if (t == 0) {
        float y0 = e5b[0], y1 = e5b[1];
        for (int k = 0; k < 32; ++k) {
            y0 += h4[k] * e5w[2 * k];
            y1 += h4[k] * e5w[2 * k + 1];
        }
        float m = fmaxf(y0, y1);
        float l = m + logf(expf(y0 - m) + expf(y1 - m));
        out[2 * g] = y0 - l;
        out[2 * g + 1] = y1 - l;
    }
}

extern "C" void kernel_launch(void* const* d_in, const int* in_sizes, int n_in,
                              void* d_out, int out_size, void* d_ws, size_t ws_size,
                              hipStream_t stream) {
    const int*   node_feat = (const int*)d_in[0];
    const int*   edge_src  = (const int*)d_in[1];
    const int*   edge_dst  = (const int*)d_in[2];
    const int*   graph_ids = (const int*)d_in[3];
    const float* emb  = (const float*)d_in[4];
    const float* W1   = (const float*)d_in[5];
    const float* b1   = (const float*)d_in[6];
    const float* W2   = (const float*)d_in[7];
    const float* b2   = (const float*)d_in[8];
    const float* e1_w = (const float*)d_in[9];
    const float* e1_b = (const float*)d_in[10];
    const float* e2_w = (const float*)d_in[11];
    const float* e2_b = (const float*)d_in[12];
    const float* e3_w = (const float*)d_in[13];
    const float* e3_b = (const float*)d_in[14];
    const float* e4_w = (const float*)d_in[15];
    const float* e4_b = (const float*)d_in[16];
    const float* e5_w = (const float*)d_in[17];
    const float* e5_b = (const float*)d_in[18];
    const float* bn0_g = (const float*)d_in[19];
    const float* bn0_b = (const float*)d_in[20];
    const float* bn1_g = (const float*)d_in[21];
    const float* bn1_b = (const float*)d_in[22];
    float* out = (float*)d_out;

    // workspace layout
    float* ws = (float*)d_ws;
    float* bufA = ws;                                                     // N*H f32 (h2)
    __hip_bfloat16* h1bf = (__hip_bfloat16*)(bufA + (size_t)N_NODES * H); // N*H bf16
    __hip_bfloat16* aggbf = h1bf + (size_t)N_NODES * H;                   // N_PAD*H bf16
    int*   cntO = (int*)(aggbf + (size_t)N_PAD * H);                      // 50000
    unsigned long long* wc = (unsigned long long*)(cntO + N_NODES);       // N*32 u64
    float* oi   = (float*)(wc + (size_t)N_NODES * VOCAB);
    float* ii   = oi + N_NODES;
    int*   cntI = (int*)(ii + N_NODES);
    int*   row_ptr = cntI + N_NODES;                                      // 50001 -> pad 50048
    int*   col  = row_ptr + 50048;                                        // 600000
    unsigned char* binbase = (unsigned char*)(col + N_EDGES);             // N*32
    unsigned char* rank8   = binbase + (size_t)N_NODES * VOCAB;           // 600000
    float* hg   = (float*)(rank8 + ((N_EDGES + 63) & ~63));
    float* t1   = hg + N_GRAPHS * H;
    float* t2   = t1 + N_GRAPHS * H;
    float* stats = t2 + N_GRAPHS * H;                                     // 512
    int*   bsum  = (int*)(stats + 4 * H);                                 // 256
    float* emb1  = (float*)(bsum + 256);                                  // 4096
    __hip_bfloat16* w2t = (__hip_bfloat16*)(emb1 + VOCAB * H);            // 16384 bf16

    // one memset covers cntO + wc (contiguous)
    hipMemsetAsync(cntO, 0, N_NODES * sizeof(int) + (size_t)N_NODES * VOCAB * 8, stream);

    const int eb = (N_EDGES + 255) / 256;
    k_countO<<<eb, 256, 0, stream>>>(edge_src, cntO, N_EDGES);
    k_oi<<<SCAN_BLOCKS, 256, 0, stream>>>(cntO, oi, N_NODES);
    k_emb1<<<VOCAB, 128, 0, stream>>>(emb, W1, emb1);
    k_w2t<<<H, 128, 0, stream>>>(W2, w2t);
    k_hist64<<<eb, 256, 0, stream>>>(edge_src, edge_dst, node_feat, oi, wc, rank8, N_EDGES);
    k_nodebins<<<(N_NODES + 3) / 4, 256, 0, stream>>>(wc, cntI, binbase, N_NODES);
    k_blocksum<<<SCAN_BLOCKS, 256, 0, stream>>>(cntI, bsum, N_NODES);
    k_scanbsum<<<1, 256, 0, stream>>>(bsum, row_ptr + N_NODES, SCAN_BLOCKS);
    k_scatterscan<<<SCAN_BLOCKS, 256, 0, stream>>>(cntI, bsum, row_ptr, ii, N_NODES);
    k_fill2<<<eb, 256, 0, stream>>>(edge_src, edge_dst, node_feat, row_ptr, binbase, rank8, col, N_EDGES);

    // layer 1: h1 = relu(ii*(w@emb1)+b1)*oi -> bf16
    k_h1<<<(N_NODES + H1_NODES - 1) / H1_NODES, 256, 0, stream>>>(wc, emb1, ii, oi, b1, h1bf, N_NODES);

    // layer 2: gather (bf16 out) -> MFMA transform (f32 out)
    const int gb = (N_NODES * 64 + 255) / 256;
    k_gather_bf<<<gb, 256, 0, stream>>>(h1bf, row_ptr, col, aggbf, N_NODES);
    k_transform_mfma<<<(N_NODES + 63) / 64, 256, 0, stream>>>(aggbf, w2t, ii, b2, bufA, N_NODES);

    // pooling
    k_pool<<<N_GRAPHS, 128, 0, stream>>>(bufA, graph_ids, hg, N_NODES);

    // MLP head
    k_mlp1<<<N_GRAPHS, 128, 0, stream>>>(hg, e1_w, e1_b, t1);
    k_bnstat<<<H, 256, 0, stream>>>(t1, stats, N_GRAPHS);
    k_mlp2bn<<<N_GRAPHS, 128, 0, stream>>>(t1, stats, bn0_g, bn0_b, e2_w, e2_b, t2);
    k_bnstat<<<H, 256, 0, stream>>>(t2, stats + 2 * H, N_GRAPHS);
    k_head<<<N_GRAPHS, 128, 0, stream>>>(t2, stats + 2 * H, bn1_g, bn1_b,
                                         e3_w, e3_b, e4_w, e4_b, e5_w, e5_b, out);
}

// Round 9
// 220.569 us; speedup vs baseline: 2.0808x; 1.0442x over previous
//
#include <hip/hip_runtime.h>
#include <hip/hip_bf16.h>
#include <math.h>

#define N_NODES 50000
#define N_PAD   50048
#define N_EDGES 600000
#define N_GRAPHS 1024
#define H 128
#define VOCAB 32
#define BN_EPS 1e-5f
#define SCAN_BLOCKS ((N_NODES + 255) / 256)   // 196
#define H1_NODES 64
#define EB ((N_EDGES + 255) / 256)            // 2344

typedef short bf8_t __attribute__((ext_vector_type(8)));
typedef float f4_t __attribute__((ext_vector_type(4)));

// ---------------- pass 1: out-degree count + weight prep (fused) ----------------
// blocks [0,EB): cntO[src]++ ; blocks [EB,EB+32): emb1 = emb@W1 ; [EB+32,EB+160): W2^T bf16
__global__ void k_count_prep(const int* __restrict__ src, int* __restrict__ cntO,
                             const float* __restrict__ emb, const float* __restrict__ W1,
                             float* __restrict__ emb1,
                             const float* __restrict__ W2, __hip_bfloat16* __restrict__ w2t) {
    int b = blockIdx.x;
    int t = threadIdx.x;
    if (b < EB) {
        int i = b * 256 + t;
        if (i < N_EDGES) atomicAdd(&cntO[src[i]], 1);
    } else if (b < EB + 32) {
        if (t < 128) {
            int v = b - EB;
            float acc = 0.f;
            for (int k = 0; k < H; ++k) acc += emb[v * H + k] * W1[k * H + t];
            emb1[v * H + t] = acc;
        }
    } else {
        if (t < 128) {
            int k = b - EB - 32;
            w2t[(size_t)t * H + k] = __float2bfloat16(W2[(size_t)k * H + t]);
        }
    }
}

// ---------------- pass 2: fused histogram + in-degree (64-bit atomics) ----------------
__global__ void k_hist64(const int* __restrict__ src, const int* __restrict__ dst,
                         const int* __restrict__ feat, const int* __restrict__ cntO,
                         unsigned long long* __restrict__ wc,
                         unsigned char* __restrict__ rank8, int E) {
    int i = blockIdx.x * blockDim.x + threadIdx.x;
    if (i >= E) return;
    int s = src[i], d = dst[i], v = feat[s];
    float o = rsqrtf(fmaxf((float)cntO[s], 1.f));
    unsigned long long q = (unsigned long long)__float2uint_rn(o * 16777216.0f);
    unsigned long long old = atomicAdd(&wc[(size_t)d * VOCAB + v], (1ULL << 40) | q);
    rank8[i] = (unsigned char)(old >> 40);
}

// ---------------- pass 3: per-node bin scan + cntI + per-256-node block sums ----------------
// 196 blocks x 256 threads; block handles 256 nodes; wave handles 2 nodes/iter (32-lane scan)
__global__ void k_nodebins(const unsigned long long* __restrict__ wc,
                           int* __restrict__ cntI, unsigned char* __restrict__ binbase,
                           int* __restrict__ bsum, int n) {
    __shared__ int scnt[256];
    int t = threadIdx.x;
    int wave = t >> 6, lane = t & 63;
    int sub = lane >> 5;       // 0/1: which node of the pair
    int l32 = lane & 31;
    int nodeBase = blockIdx.x * 256;
#pragma unroll 4
    for (int it = 0; it < 32; ++it) {
        int local = wave * 64 + it * 2 + sub;
        int node = nodeBase + local;
        int c = 0;
        if (node < n && l32 < VOCAB)
            c = (int)(wc[(size_t)node * VOCAB + l32] >> 40);
        int inc = c;
#pragma unroll
        for (int off = 1; off < VOCAB; off <<= 1) {
            int u = __shfl_up(inc, off, 32);
            if (l32 >= off) inc += u;
        }
        if (node < n && l32 < VOCAB)
            binbase[(size_t)node * VOCAB + l32] = (unsigned char)(inc - c);
        if (l32 == VOCAB - 1) scnt[local] = (node < n) ? inc : 0;
    }
    __syncthreads();
    int node = nodeBase + t;
    if (node < n) cntI[node] = scnt[t];
    // block reduce -> bsum
    __shared__ int red[256];
    red[t] = scnt[t];
    __syncthreads();
    for (int off = 128; off > 0; off >>= 1) {
        if (t < off) red[t] += red[t + off];
        __syncthreads();
    }
    if (t == 0) bsum[blockIdx.x] = red[0];
}

__global__ void k_scanbsum(int* __restrict__ bsum, int* __restrict__ row_ptr_last, int nb) {
    __shared__ int sh[256];
    int t = threadIdx.x;
    int v = (t < nb) ? bsum[t] : 0;
    sh[t] = v;
    __syncthreads();
    for (int off = 1; off < 256; off <<= 1) {
        int u = (t >= off) ? sh[t - off] : 0;
        __syncthreads();
        sh[t] += u;
        __syncthreads();
    }
    if (t < nb) bsum[t] = sh[t] - v;
    if (t == nb - 1) *row_ptr_last = sh[t];
}

__global__ void k_scatterscan(const int* __restrict__ cntI, const int* __restrict__ bsum,
                              int* __restrict__ row_ptr, float* __restrict__ ii, int n) {
    __shared__ int sh[256];
    int i = blockIdx.x * 256 + threadIdx.x;
    int t = threadIdx.x;
    int v = (i < n) ? cntI[i] : 0;
    sh[t] = v;
    __syncthreads();
    for (int off = 1; off < 256; off <<= 1) {
        int u = (t >= off) ? sh[t - off] : 0;
        __syncthreads();
        sh[t] += u;
        __syncthreads();
    }
    if (i < n) {
        row_ptr[i] = bsum[blockIdx.x] + sh[t] - v;
        ii[i] = rsqrtf(fmaxf((float)v, 1.f));
    }
}

// ---------------- pass 4 (fused): atomic-free CSR fill  +  layer-1 h1 compute ----------------
#define H1_BLOCKS ((N_NODES + H1_NODES - 1) / H1_NODES)   // 782
__global__ void k_fill_h1(const int* __restrict__ src, const int* __restrict__ dst,
                          const int* __restrict__ feat, const int* __restrict__ row_ptr,
                          const unsigned char* __restrict__ binbase,
                          const unsigned char* __restrict__ rank8,
                          int* __restrict__ col,
                          const unsigned long long* __restrict__ wc,
                          const float* __restrict__ emb1,
                          const float* __restrict__ ii, const int* __restrict__ cntO,
                          const float* __restrict__ b1, __hip_bfloat16* __restrict__ h1) {
    __shared__ float wl[H1_NODES * VOCAB];
    __shared__ float sii[H1_NODES], soi[H1_NODES];
    int tid = threadIdx.x;
    if (blockIdx.x < EB) {
        int i = blockIdx.x * 256 + tid;
        if (i < N_EDGES) {
            int s = src[i], d = dst[i], v = feat[s];
            int slot = row_ptr[d] + (int)binbase[(size_t)d * VOCAB + v] + (int)rank8[i];
            col[slot] = s;
        }
        return;
    }
    int hb = blockIdx.x - EB;
    int j = tid & 127;
    int g = tid >> 7;
    float ev[VOCAB];
#pragma unroll
    for (int v = 0; v < VOCAB; ++v) ev[v] = emb1[v * H + j];
    float bj = b1[j];

    int node0 = hb * H1_NODES;
    int nn = min(H1_NODES, N_NODES - node0);
    const unsigned long long* wsrc = wc + (size_t)node0 * VOCAB;
    for (int i = tid; i < nn * VOCAB; i += 256) {
        unsigned long long p = wsrc[i];
        float lo = (float)((unsigned)p & 0xFFFFFFu);
        float hi = (float)((unsigned)(p >> 24) & 0xFFFFu);
        wl[i] = fmaf(lo, 1.0f / 16777216.0f, hi);
    }
    for (int i = tid; i < nn; i += 256) {
        sii[i] = ii[node0 + i];
        soi[i] = rsqrtf(fmaxf((float)cntO[node0 + i], 1.f));
    }
    __syncthreads();

    int rbeg = g * 32;
    int rend = min(rbeg + 32, nn);
    for (int r = rbeg; r < rend; ++r) {
        const float4* wr = (const float4*)(wl + r * VOCAB);
        float acc = 0.f;
#pragma unroll
        for (int q = 0; q < VOCAB / 4; ++q) {
            float4 w4 = wr[q];
            acc += w4.x * ev[4 * q] + w4.y * ev[4 * q + 1]
                 + w4.z * ev[4 * q + 2] + w4.w * ev[4 * q + 3];
        }
        float val = fmaxf(acc * sii[r] + bj, 0.f);
        h1[(size_t)(node0 + r) * H + j] = __float2bfloat16(val * soi[r]);
    }
}

// ---------------- layer-2 gather: 2 nodes per wave, 8B loads, 16 rows in flight ----------------
__global__ void k_gather_bf(const __hip_bfloat16* __restrict__ h,
                            const int* __restrict__ row_ptr, const int* __restrict__ col,
                            __hip_bfloat16* __restrict__ out, int n) {
    int gid = blockIdx.x * blockDim.x + threadIdx.x;
    int wid = gid >> 6;
    int lane = gid & 63;
    int node = wid * 2 + (lane >> 5);
    int l32 = lane & 31;
    if (node >= n) return;
    int beg = row_ptr[node];
    int end = row_ptr[node + 1];
    int co = l32 * 4;            // 4 channels per lane
    float a0 = 0.f, a1 = 0.f, a2 = 0.f, a3 = 0.f;
    int e = beg;
    for (; e + 8 <= end; e += 8) {
#pragma unroll
        for (int k = 0; k < 8; ++k) {
            int s = col[e + k];
            uint2 v = *(const uint2*)(h + (size_t)s * H + co);
            float2 f0 = __bfloat1622float2(*(__hip_bfloat162*)&v.x);
            float2 f1 = __bfloat1622float2(*(__hip_bfloat162*)&v.y);
            a0 += f0.x; a1 += f0.y; a2 += f1.x; a3 += f1.y;
        }
    }
    for (; e < end; ++e) {
        int s = col[e];
        uint2 v = *(const uint2*)(h + (size_t)s * H + co);
        float2 f0 = __bfloat1622float2(*(__hip_bfloat162*)&v.x);
        float2 f1 = __bfloat1622float2(*(__hip_bfloat162*)&v.y);
        a0 += f0.x; a1 += f0.y; a2 += f1.x; a3 += f1.y;
    }
    __hip_bfloat162 o0 = __float22bfloat162_rn(make_float2(a0, a1));
    __hip_bfloat162 o1 = __float22bfloat162_rn(make_float2(a2, a3));
    uint2 ov;
    ov.x = *(unsigned*)&o0;
    ov.y = *(unsigned*)&o1;
    *(uint2*)(out + (size_t)node * H + co) = ov;
}

// ---------------- MFMA transform ----------------
__global__ void k_transform_mfma(const __hip_bfloat16* __restrict__ A,
                                 const __hip_bfloat16* __restrict__ WT,
                                 const float* __restrict__ ii,
                                 const float* __restrict__ b,
                                 float* __restrict__ outp, int n) {
    int wave = threadIdx.x >> 6;
    int lane = threadIdx.x & 63;
    int row0 = blockIdx.x * 64 + wave * 16;
    int rl = lane & 15;
    int kg = lane >> 4;
    f4_t acc[8];
#pragma unroll
    for (int t = 0; t < 8; ++t) acc[t] = f4_t{0.f, 0.f, 0.f, 0.f};
    const __hip_bfloat16* arow = A + (size_t)(row0 + rl) * H + kg * 8;
#pragma unroll
    for (int ks = 0; ks < 4; ++ks) {
        bf8_t a = *(const bf8_t*)(arow + ks * 32);
#pragma unroll
        for (int t = 0; t < 8; ++t) {
            bf8_t bf = *(const bf8_t*)(WT + (size_t)(t * 16 + rl) * H + ks * 32 + kg * 8);
            acc[t] = __builtin_amdgcn_mfma_f32_16x16x32_bf16(a, bf, acc[t], 0, 0, 0);
        }
    }
    int rbase = row0 + kg * 4;
#pragma unroll
    for (int r = 0; r < 4; ++r) {
        int node = rbase + r;
        if (node < n) {
            float s = ii[node];
#pragma unroll
            for (int t = 0; t < 8; ++t) {
                int c = t * 16 + rl;
                float v = acc[t][r] * s + b[c];
                outp[(size_t)node * H + c] = fmaxf(v, 0.f);
            }
        }
    }
}

// ---------------- pooling + first head GEMV (fused) ----------------
__global__ void k_poolmlp1(const float* __restrict__ h, const int* __restrict__ gid,
                           const float* __restrict__ e1w, const float* __restrict__ e1b,
                           float* __restrict__ t1, int n) {
    __shared__ int bnd[2];
    __shared__ float row[128];
    int g = blockIdx.x, t = threadIdx.x;
    if (t == 0) {
        int lo = 0, hi = n;
        while (lo < hi) { int m = (lo + hi) >> 1; if (gid[m] < g) lo = m + 1; else hi = m; }
        bnd[0] = lo;
        int lo2 = lo, hi2 = n;
        while (lo2 < hi2) { int m = (lo2 + hi2) >> 1; if (gid[m] < g + 1) lo2 = m + 1; else hi2 = m; }
        bnd[1] = lo2;
    }
    __syncthreads();
    int beg = bnd[0], end = bnd[1];
    float s = 0.f;
    for (int i = beg; i < end; ++i) s += h[(size_t)i * H + t];
    row[t] = s / fmaxf((float)(end - beg), 1.f);
    __syncthreads();
    float acc = e1b[t];
    for (int k = 0; k < H; ++k) acc += row[k] * e1w[k * H + t];
    t1[g * H + t] = acc;
}

// ---------------- BN stats / head ----------------
__global__ void k_bnstat(const float* __restrict__ x, float* __restrict__ stats, int G) {
    int c = blockIdx.x;
    float s = 0.f, s2 = 0.f;
    for (int g = threadIdx.x; g < G; g += blockDim.x) {
        float v = x[g * H + c];
        s += v; s2 += v * v;
    }
    __shared__ float rs[256], rs2[256];
    rs[threadIdx.x] = s; rs2[threadIdx.x] = s2;
    __syncthreads();
    for (int off = 128; off > 0; off >>= 1) {
        if (threadIdx.x < off) { rs[threadIdx.x] += rs[threadIdx.x + off]; rs2[threadIdx.x] += rs2[threadIdx.x + off]; }
        __syncthreads();
    }
    if (threadIdx.x == 0) {
        float mu = rs[0] / G;
        stats[c] = mu;
        stats[H + c] = rs2[0] / G - mu * mu;
    }
}

__global__ void k_mlp2bn(const float* __restrict__ t1, const float* __restrict__ stats,
                         const float* __restrict__ gam, const float* __restrict__ bet,
                         const float* __restrict__ W, const float* __restrict__ bias,
                         float* __restrict__ t2) {
    __shared__ float x[128];
    int g = blockIdx.x, t = threadIdx.x;
    float v = t1[g * H + t];
    v = (v - stats[t]) * rsqrtf(stats[H + t] + BN_EPS) * gam[t] + bet[t];
    x[t] = (v >= 0.f) ? v : 0.05f * v;
    __syncthreads();
    float acc = bias[t];
    for (int k = 0; k < H; ++k) acc += x[k] * W[k * H + t];
    t2[g * H + t] = acc;
}

__global__ void k_head(const float* __restrict__ t2, const float* __restrict__ stats,
                       const float* __restrict__ gam, const float* __restrict__ bet,
                       const float* __restrict__ e3w, const float* __restrict__ e3b,
                       const float* __restrict__ e4w, const float* __restrict__ e4b,
                       const float* __restrict__ e5w, const float* __restrict__ e5b,
                       float* __restrict__ out) {
    __shared__ float x[128], h3[64], h4[32];
    int g = blockIdx.x, t = threadIdx.x;
    float v = t2[g * H + t];
    v = (v - stats[t]) * rsqrtf(stats[H + t] + BN_EPS) * gam[t] + bet[t];
    x[t] = (v >= 0.f) ? v : 0.05f * v;
    __syncthreads();
    if (t < 64) {
        float a = e3b[t];
        for (int k = 0; k < 128; ++k) a += x[k] * e3w[k * 64 + t];
        h3[t] = (a >= 0.f) ? a : 0.1f * a;
    }
    __syncthreads();
    if (t < 32) {
        float a = e4b[t];
        for (int k = 0; k < 64; ++k) a += h3[k] * e4w[k * 32 + t];
        h4[t] = (a >= 0.f) ? a : 0.1f * a;
    }
    __syncthreads();
    if (t == 0) {
        float y0 = e5b[0], y1 = e5b[1];
        for (int k = 0; k < 32; ++k) {
            y0 += h4[k] * e5w[2 * k];
            y1 += h4[k] * e5w[2 * k + 1];
        }
        float m = fmaxf(y0, y1);
        float l = m + logf(expf(y0 - m) + expf(y1 - m));
        out[2 * g] = y0 - l;
        out[2 * g + 1] = y1 - l;
    }
}

extern "C" void kernel_launch(void* const* d_in, const int* in_sizes, int n_in,
                              void* d_out, int out_size, void* d_ws, size_t ws_size,
                              hipStream_t stream) {
    const int*   node_feat = (const int*)d_in[0];
    const int*   edge_src  = (const int*)d_in[1];
    const int*   edge_dst  = (const int*)d_in[2];
    const int*   graph_ids = (const int*)d_in[3];
    const float* emb  = (const float*)d_in[4];
    const float* W1   = (const float*)d_in[5];
    const float* b1   = (const float*)d_in[6];
    const float* W2   = (const float*)d_in[7];
    const float* b2   = (const float*)d_in[8];
    const float* e1_w = (const float*)d_in[9];
    const float* e1_b = (const float*)d_in[10];
    const float* e2_w = (const float*)d_in[11];
    const float* e2_b = (const float*)d_in[12];
    const float* e3_w = (const float*)d_in[13];
    const float* e3_b = (const float*)d_in[14];
    const float* e4_w = (const float*)d_in[15];
    const float* e4_b = (const float*)d_in[16];
    const float* e5_w = (const float*)d_in[17];
    const float* e5_b = (const float*)d_in[18];
    const float* bn0_g = (const float*)d_in[19];
    const float* bn0_b = (const float*)d_in[20];
    const float* bn1_g = (const float*)d_in[21];
    const float* bn1_b = (const float*)d_in[22];
    float* out = (float*)d_out;

    // workspace layout
    float* ws = (float*)d_ws;
    float* bufA = ws;                                                     // N*H f32 (h2)
    __hip_bfloat16* h1bf = (__hip_bfloat16*)(bufA + (size_t)N_NODES * H); // N*H bf16
    __hip_bfloat16* aggbf = h1bf + (size_t)N_NODES * H;                   // N_PAD*H bf16
    int*   cntO = (int*)(aggbf + (size_t)N_PAD * H);                      // 50000
    unsigned long long* wc = (unsigned long long*)(cntO + N_NODES);       // N*32 u64
    float* ii   = (float*)(wc + (size_t)N_NODES * VOCAB);
    int*   cntI = (int*)(ii + N_NODES);
    int*   row_ptr = cntI + N_NODES;                                      // 50001 -> pad 50048
    int*   col  = row_ptr + 50048;                                        // 600000
    unsigned char* binbase = (unsigned char*)(col + N_EDGES);             // N*32
    unsigned char* rank8   = binbase + (size_t)N_NODES * VOCAB;           // 600000
    float* t1   = (float*)(rank8 + ((N_EDGES + 63) & ~63));
    float* t2   = t1 + N_GRAPHS * H;
    float* stats = t2 + N_GRAPHS * H;                                     // 512
    int*   bsum  = (int*)(stats + 4 * H);                                 // 256
    float* emb1  = (float*)(bsum + 256);                                  // 4096
    __hip_bfloat16* w2t = (__hip_bfloat16*)(emb1 + VOCAB * H);            // 16384 bf16

    // zero cntO + wc (contiguous)
    hipMemsetAsync(cntO, 0, N_NODES * sizeof(int) + (size_t)N_NODES * VOCAB * 8, stream);

    k_count_prep<<<EB + 160, 256, 0, stream>>>(edge_src, cntO, emb, W1, emb1, W2, w2t);
    k_hist64<<<EB, 256, 0, stream>>>(edge_src, edge_dst, node_feat, cntO, wc, rank8, N_EDGES);
    k_nodebins<<<SCAN_BLOCKS, 256, 0, stream>>>(wc, cntI, binbase, bsum, N_NODES);
    k_scanbsum<<<1, 256, 0, stream>>>(bsum, row_ptr + N_NODES, SCAN_BLOCKS);
    k_scatterscan<<<SCAN_BLOCKS, 256, 0, stream>>>(cntI, bsum, row_ptr, ii, N_NODES);
    k_fill_h1<<<EB + H1_BLOCKS, 256, 0, stream>>>(edge_src, edge_dst, node_feat, row_ptr,
                                                  binbase, rank8, col,
                                                  wc, emb1, ii, cntO, b1, h1bf);

    // layer 2
    const int gb = ((N_NODES + 1) / 2 * 64 + 255) / 256;
    k_gather_bf<<<gb, 256, 0, stream>>>(h1bf, row_ptr, col, aggbf, N_NODES);
    k_transform_mfma<<<(N_NODES + 63) / 64, 256, 0, stream>>>(aggbf, w2t, ii, b2, bufA, N_NODES);

    // pooling + head
    k_poolmlp1<<<N_GRAPHS, 128, 0, stream>>>(bufA, graph_ids, e1_w, e1_b, t1, N_NODES);
    k_bnstat<<<H, 256, 0, stream>>>(t1, stats, N_GRAPHS);
    k_mlp2bn<<<N_GRAPHS, 128, 0, stream>>>(t1, stats, bn0_g, bn0_b, e2_w, e2_b, t2);
    k_bnstat<<<H, 256, 0, stream>>>(t2, stats + 2 * H, N_GRAPHS);
    k_head<<<N_GRAPHS, 128, 0, stream>>>(t2, stats + 2 * H, bn1_g, bn1_b,
                                         e3_w, e3_b, e4_w, e4_b, e5_w, e5_b, out);
}